// Round 1
// baseline (4002.089 us; speedup 1.0000x reference)
//
#include <hip/hip_runtime.h>
#include <math.h>

// Problem constants (fixed dataset, key=0)
#define CAPT 20480              // per-type compacted-node capacity (actual ~16.7k, sigma ~118)
#define R2   (2*CAPT)           // total GRU rows (map region [0,CAPT), mem region [CAPT,R2))

__device__ __forceinline__ float sigmoidf_(float x){ return 1.f/(1.f+expf(-x)); }
__device__ __forceinline__ float geluf_(float x){
  const float c = 0.7978845608028654f;
  float t = tanhf(c*(x + 0.044715f*x*x*x));
  return 0.5f*x*(1.f+t);
}

// ---------------- init h = [one_hot(type,6) | zeros(64)] ----------------
__global__ void k_init_h(const int* __restrict__ type_idx, float* __restrict__ h, int N){
  int g = blockIdx.x*256 + threadIdx.x;
  if (g >= N*70) return;
  int n = g / 70, c = g - n*70;
  float v = 0.f;
  if (c < 6) v = (type_idx[n] == c) ? 1.f : 0.f;
  h[g] = v;
}

// ---------------- compact node lists by type ----------------
__global__ void k_compact(const int* __restrict__ type_idx, int* __restrict__ idxcat,
                          int* __restrict__ cnt, int N){
  int n = blockIdx.x*256 + threadIdx.x;
  if (n >= N) return;
  int t = type_idx[n];
  if (t == 0){ int p = atomicAdd(&cnt[0],1); if (p < CAPT) idxcat[p] = n; }
  else if (t == 5){ int p = atomicAdd(&cnt[1],1); if (p < CAPT) idxcat[CAPT+p] = n; }
}

// ---------------- GRU weight prep: BgruT[typ][k][m] (k<64: Wi^T, else Wh^T), bsum = bi+bh ----
__global__ void k_prep_gru(const float* __restrict__ Wi_map, const float* __restrict__ Wh_map,
                           const float* __restrict__ bi_map, const float* __restrict__ bh_map,
                           const float* __restrict__ Wi_mem, const float* __restrict__ Wh_mem,
                           const float* __restrict__ bi_mem, const float* __restrict__ bh_mem,
                           float* __restrict__ BgruT, float* __restrict__ bsum){
  int g = blockIdx.x*256 + threadIdx.x;
  if (g < 2*128*192){
    int typ = g / (128*192); int rem = g - typ*(128*192);
    int k = rem / 192, m = rem - k*192;
    const float* Wi = typ ? Wi_mem : Wi_map;
    const float* Wh = typ ? Wh_mem : Wh_map;
    BgruT[g] = (k < 64) ? Wi[m*64 + k] : Wh[m*64 + (k-64)];
  }
  if (g < 2*192){
    int typ = g / 192, m = g - typ*192;
    bsum[g] = (typ? bi_mem:bi_map)[m] + (typ? bh_mem:bh_map)[m];
  }
}

// ---------------- GRU step GEMM: G[r,0:192] = [emb(x_s) | Hprev] @ BgruT (+bsum)
//                  and (col-block 2) Ghn[r,0:64] = Hprev @ Whn^T (+bh_n) ----------------
__global__ __launch_bounds__(256) void k_gru_gemm(
    const int* __restrict__ idxcat, const int* __restrict__ tokens,
    const float* __restrict__ embed, const float* __restrict__ BgruT,
    const float* __restrict__ bsum, const float* __restrict__ bh_map,
    const float* __restrict__ bh_mem, const float* __restrict__ Hprev,
    float* __restrict__ G, float* __restrict__ Ghn, int s)
{
  int rb = blockIdx.x * 64;
  int cb = blockIdx.y * 64;
  if (idxcat[rb] < 0 && idxcat[rb+63] < 0) return;   // fully-pad block: skip (outputs unread)
  __shared__ float As[16][68];
  __shared__ float Bs[16][68];
  int t = threadIdx.x, tx = t & 15, ty = t >> 4;
  int isMem = (rb >= CAPT) ? 1 : 0;
  const float* Bp = BgruT + (isMem ? 128*192 : 0);
  const bool doHn = (cb == 128);
  float acc[4][4] = {{0.f}}; float accH[4][4] = {{0.f}};
  for (int k0 = 0; k0 < 128; k0 += 16){
    for (int i=0;i<4;i++){
      int idx = t + i*256; int r = idx >> 4, kk = idx & 15;
      int gr = rb + r, k = k0 + kk;
      float v;
      if (k < 64){
        int nd = idxcat[gr]; if (nd < 0) nd = 0;
        int tok = tokens[nd*8 + s];
        v = embed[tok*64 + k];
      } else {
        v = Hprev[gr*64 + (k-64)];
      }
      As[kk][r] = v;
    }
    for (int i=0;i<4;i++){
      int idx = t + i*256; int kk = idx >> 6, c = idx & 63;
      Bs[kk][c] = Bp[(k0+kk)*192 + cb + c];
    }
    __syncthreads();
    if (doHn && k0 >= 64){
      #pragma unroll
      for (int kk=0;kk<16;kk++){
        float4 a4 = *reinterpret_cast<const float4*>(&As[kk][ty<<2]);
        float4 b4 = *reinterpret_cast<const float4*>(&Bs[kk][tx<<2]);
        float a[4]={a4.x,a4.y,a4.z,a4.w}, b[4]={b4.x,b4.y,b4.z,b4.w};
        #pragma unroll
        for(int i=0;i<4;i++)
          #pragma unroll
          for(int j=0;j<4;j++){ float p=a[i]*b[j]; acc[i][j]+=p; accH[i][j]+=p; }
      }
    } else {
      #pragma unroll
      for (int kk=0;kk<16;kk++){
        float4 a4 = *reinterpret_cast<const float4*>(&As[kk][ty<<2]);
        float4 b4 = *reinterpret_cast<const float4*>(&Bs[kk][tx<<2]);
        float a[4]={a4.x,a4.y,a4.z,a4.w}, b[4]={b4.x,b4.y,b4.z,b4.w};
        #pragma unroll
        for(int i=0;i<4;i++)
          #pragma unroll
          for(int j=0;j<4;j++) acc[i][j] += a[i]*b[j];
      }
    }
    __syncthreads();
  }
  const float* bh = isMem ? bh_mem : bh_map;
  const float* bs = bsum + (isMem ? 192 : 0);
  for (int i=0;i<4;i++){
    int gr = rb + (ty<<2) + i;
    for (int j=0;j<4;j++){
      int gc = cb + (tx<<2) + j;
      G[gr*192 + gc] = acc[i][j] + bs[gc];
      if (doHn) Ghn[gr*64 + (gc-128)] = accH[i][j] + bh[gc];
    }
  }
}

// ---------------- GRU pointwise: h' = (1-z)*n + z*h ----------------
__global__ void k_gru_pointwise(const float* __restrict__ G, const float* __restrict__ Ghn,
                                const float* __restrict__ Hprev, float* __restrict__ Hnext){
  int g = blockIdx.x*256 + threadIdx.x;     // exactly R2*64 threads
  int row = g >> 6, u = g & 63;
  const float* Gr = G + row*192;
  float r  = sigmoidf_(Gr[u]);
  float z  = sigmoidf_(Gr[64+u]);
  float hn = Ghn[g];
  float n  = tanhf(Gr[128+u] + (r - 1.f)*hn);
  Hnext[g] = (1.f - z)*n + z*Hprev[g];
}

// ---------------- scatter final hidden into h[:,6:70] ----------------
__global__ void k_scatter_h(const int* __restrict__ idxcat, const float* __restrict__ Hlast,
                            float* __restrict__ h){
  int g = blockIdx.x*256 + threadIdx.x;     // R2*64
  int row = g >> 6, u = g & 63;
  int nd = idxcat[row];
  if (nd >= 0) h[nd*70 + 6 + u] = Hlast[g];
}

// ---------------- CSR build (by dst), edges reused by all 8 MP layers ----------------
__global__ void k_count(const int* __restrict__ edst, int* __restrict__ deg, int TE){
  int i = blockIdx.x*256 + threadIdx.x;
  if (i < TE) atomicAdd(&deg[edst[i]], 1);
}
__global__ void k_scan1(const int* __restrict__ deg, int* __restrict__ off,
                        int* __restrict__ bsum, int N){
  __shared__ int sh[256];
  int t = threadIdx.x; int base = blockIdx.x*2048;
  int v[8]; int s = 0;
  for (int i=0;i<8;i++){ int g = base + t*8 + i; int x = (g<N)? deg[g] : 0; v[i]=x; s+=x; }
  sh[t]=s; __syncthreads();
  for (int o=1;o<256;o<<=1){ int x = (t>=o)? sh[t-o]:0; __syncthreads(); sh[t]+=x; __syncthreads(); }
  if (t==255) bsum[blockIdx.x] = sh[255];
  int run = sh[t]-s;
  for (int i=0;i<8;i++){ int g = base + t*8 + i; if (g<N) off[g]=run; run+=v[i]; }
}
__global__ void k_scan2(int* bsum, int nb){
  if (threadIdx.x==0 && blockIdx.x==0){ int run=0; for(int b=0;b<nb;b++){ int x=bsum[b]; bsum[b]=run; run+=x; } }
}
__global__ void k_scan3(int* __restrict__ off, const int* __restrict__ bsum, int N, int total){
  int g = blockIdx.x*256+threadIdx.x;
  if (g < N) off[g] += bsum[g>>11];
  if (g == 0) off[N] = total;
}
__global__ void k_fill(const int* __restrict__ esrc, const int* __restrict__ edst,
                       const int* __restrict__ off, int* __restrict__ cur,
                       int* __restrict__ edata, int TE, int E){
  int i = blockIdx.x*256 + threadIdx.x;
  if (i >= TE) return;
  int d = edst[i];
  int pos = off[d] + atomicAdd(&cur[d], 1);
  edata[pos] = (esrc[i] << 1) | (i >= E ? 1 : 0);   // pack (src, edge-type)
}

// ---------------- generic tiled fp32 GEMM, A = up to 3 concatenated segments ----------------
// C[rows, cols] = act( [A0|A1|A2] @ B + bias ), B row-major [K, ldB], act: 0 none, 1 gelu, 2 tanh
__global__ __launch_bounds__(256) void gemm3(
    const float* __restrict__ A0, int w0,
    const float* __restrict__ A1, int w1,
    const float* __restrict__ A2, int w2,
    const float* __restrict__ B, int ldB,
    const float* __restrict__ bias,
    float* __restrict__ C, int ldC,
    int rows, int cols, int act)
{
  int K = w0 + w1 + w2;
  int rb = blockIdx.x * 64;
  int cb = blockIdx.y * 64;
  if (rb >= rows) return;
  __shared__ float As[16][68];
  __shared__ float Bs[16][68];
  int t = threadIdx.x, tx = t & 15, ty = t >> 4;
  float acc[4][4] = {{0.f}};
  for (int k0 = 0; k0 < K; k0 += 16){
    for (int i=0;i<4;i++){
      int idx = t + i*256; int r = idx >> 4, kk = idx & 15;
      int gr = rb + r, k = k0 + kk;
      float v = 0.f;
      if (gr < rows && k < K){
        if (k < w0)            v = A0[gr*w0 + k];
        else if (k < w0 + w1)  v = A1[gr*w1 + (k - w0)];
        else                   v = A2[gr*w2 + (k - w0 - w1)];
      }
      As[kk][r] = v;
    }
    for (int i=0;i<4;i++){
      int idx = t + i*256; int kk = idx >> 6, c = idx & 63;
      int k = k0 + kk, gc = cb + c;
      Bs[kk][c] = (k < K && gc < cols) ? B[k*ldB + gc] : 0.f;
    }
    __syncthreads();
    #pragma unroll
    for (int kk=0;kk<16;kk++){
      float4 a4 = *reinterpret_cast<const float4*>(&As[kk][ty<<2]);
      float4 b4 = *reinterpret_cast<const float4*>(&Bs[kk][tx<<2]);
      float a[4]={a4.x,a4.y,a4.z,a4.w}, b[4]={b4.x,b4.y,b4.z,b4.w};
      #pragma unroll
      for(int i=0;i<4;i++)
        #pragma unroll
        for(int j=0;j<4;j++) acc[i][j] += a[i]*b[j];
    }
    __syncthreads();
  }
  for (int i=0;i<4;i++){
    int gr = rb + (ty<<2) + i;
    if (gr >= rows) continue;
    for (int j=0;j<4;j++){
      int gc = cb + (tx<<2) + j;
      if (gc >= cols) continue;
      float v = acc[i][j] + bias[gc];
      if (act == 1) v = geluf_(v);
      else if (act == 2) v = tanhf(v);
      C[gr*ldC + gc] = v;
    }
  }
}

// ---------------- CSR gather + segment max (one wave per node) ----------------
__global__ __launch_bounds__(256) void k_aggregate(
    const int* __restrict__ off, const int* __restrict__ edata,
    const float* __restrict__ P0, const float* __restrict__ P1,
    float* __restrict__ agg, int M, int N)
{
  int node = blockIdx.x*4 + (threadIdx.x >> 6);
  int lane = threadIdx.x & 63;
  if (node >= N) return;
  int e0 = off[node], e1 = off[node+1];
  float v0 = -INFINITY, v1 = -INFINITY, v2 = -INFINITY;
  for (int e = e0; e < e1; e++){
    int w = edata[e];
    const float* row = ((w & 1) ? P1 : P0) + (w >> 1) * M;
    v0 = fmaxf(v0, row[lane]);
    if (64  + lane < M) v1 = fmaxf(v1, row[64 + lane]);
    if (128 + lane < M) v2 = fmaxf(v2, row[128 + lane]);
  }
  float* o = agg + node * M;
  o[lane] = (v0 == -INFINITY) ? 0.f : v0;
  if (64  + lane < M) o[64 + lane]  = (v1 == -INFINITY) ? 0.f : v1;
  if (128 + lane < M) o[128 + lane] = (v2 == -INFINITY) ? 0.f : v2;
}

// ---------------- final head: out = relu(h[entry]@W1+b1)@W2+b2 ----------------
__global__ void k_head(const float* __restrict__ h, const int* __restrict__ entry,
                       const float* __restrict__ W1, const float* __restrict__ b1,
                       const float* __restrict__ W2, const float* __restrict__ b2,
                       float* __restrict__ out){
  __shared__ float x[70], x1[70];
  int t = threadIdx.x;
  if (t < 70) x[t] = h[(*entry)*70 + t];
  __syncthreads();
  if (t < 70){
    float s = b1[t];
    for (int i=0;i<70;i++) s += x[i]*W1[i*70 + t];
    x1[t] = fmaxf(s, 0.f);
  }
  __syncthreads();
  if (t < 640){
    float s = b2[t];
    for (int i=0;i<70;i++) s += x1[i]*W2[i*640 + t];
    out[t] = s;
  }
}

extern "C" void kernel_launch(void* const* d_in, const int* in_sizes, int n_in,
                              void* d_out, int out_size, void* d_ws, size_t ws_size,
                              hipStream_t stream) {
  const int*   tokens   = (const int*)d_in[0];
  const int*   type_idx = (const int*)d_in[1];
  const int*   esrc     = (const int*)d_in[2];
  const int*   edst     = (const int*)d_in[3];
  const int*   entry    = (const int*)d_in[4];
  const float* embed    = (const float*)d_in[5];
  const float* Wi_map   = (const float*)d_in[6];
  const float* Wh_map   = (const float*)d_in[7];
  const float* bi_map   = (const float*)d_in[8];
  const float* bh_map   = (const float*)d_in[9];
  const float* Wi_mem   = (const float*)d_in[10];
  const float* Wh_mem   = (const float*)d_in[11];
  const float* bi_mem   = (const float*)d_in[12];
  const float* bh_mem   = (const float*)d_in[13];
  const float* Wm_plain = (const float*)d_in[14];
  const float* bm_plain = (const float*)d_in[15];
  const float* Wu_plain = (const float*)d_in[16];
  const float* bu_plain = (const float*)d_in[17];
  const float* Wm_ar    = (const float*)d_in[18];
  const float* bm_ar    = (const float*)d_in[19];
  const float* Wu_ar    = (const float*)d_in[20];
  const float* bu_ar    = (const float*)d_in[21];
  const float* W1 = (const float*)d_in[22];
  const float* b1 = (const float*)d_in[23];
  const float* W2 = (const float*)d_in[24];
  const float* b2 = (const float*)d_in[25];
  float* out = (float*)d_out;

  const int N  = in_sizes[1];      // 100000
  const int TE = in_sizes[2];      // 500000 (T*E)
  const int E  = TE / 2;

  // ---- ws layout (~255 MB) ----
  char* p = (char*)d_ws;
  auto alloc = [&](size_t bytes)->char* { char* r = p; p += (bytes + 255) & ~(size_t)255; return r; };
  float* hA   = (float*)alloc((size_t)N*70*4);
  float* hB   = (float*)alloc((size_t)N*70*4);
  float* hC   = (float*)alloc((size_t)N*70*4);
  float* P2_0 = (float*)alloc((size_t)N*140*4);
  float* P2_1 = (float*)alloc((size_t)N*140*4);
  float* agg  = (float*)alloc((size_t)N*140*4);
  int* deg    = (int*)alloc((size_t)N*4);
  int* curp   = (int*)alloc((size_t)N*4);
  int* off    = (int*)alloc((size_t)(N+8)*4);
  int* edata  = (int*)alloc((size_t)TE*4);
  int* sbsum  = (int*)alloc(256*4);
  int* cnt    = (int*)alloc(16*4);
  int* idxcat = (int*)alloc((size_t)R2*4);
  float* BgruT= (float*)alloc(2*128*192*4);
  float* bsumv= (float*)alloc(2*192*4);
  // GRU scratch overlaid on MP buffers (GRU finishes before MP starts)
  float* G    = P2_0;                 // [R2,192]
  float* Ghn  = P2_1;                 // [R2,64]
  float* Hb0  = P2_1 + (size_t)R2*64; // [R2,64]
  float* Hb1  = Hb0  + (size_t)R2*64; // [R2,64]

  // ---- init ----
  hipMemsetAsync(idxcat, 0xFF, (size_t)R2*4, stream);           // -1 sentinels
  hipMemsetAsync(cnt,    0,    16*4, stream);
  hipMemsetAsync(deg,    0,    (size_t)N*4, stream);
  hipMemsetAsync(curp,   0,    (size_t)N*4, stream);
  hipMemsetAsync(Hb0,    0,    (size_t)R2*64*4, stream);        // h0 = 0
  k_prep_gru<<<(2*128*192+255)/256, 256, 0, stream>>>(Wi_map,Wh_map,bi_map,bh_map,
                                                      Wi_mem,Wh_mem,bi_mem,bh_mem, BgruT, bsumv);
  k_init_h<<<(N*70+255)/256, 256, 0, stream>>>(type_idx, hA, N);
  k_compact<<<(N+255)/256, 256, 0, stream>>>(type_idx, idxcat, cnt, N);

  // ---- CSR build ----
  k_count<<<(TE+255)/256, 256, 0, stream>>>(edst, deg, TE);
  int nb = (N + 2047)/2048;
  k_scan1<<<nb, 256, 0, stream>>>(deg, off, sbsum, N);
  k_scan2<<<1, 64, 0, stream>>>(sbsum, nb);
  k_scan3<<<(N+255)/256, 256, 0, stream>>>(off, sbsum, N, TE);
  k_fill<<<(TE+255)/256, 256, 0, stream>>>(esrc, edst, off, curp, edata, TE, E);

  // ---- GRU: 8 steps (map + mem regions in one launch) ----
  float* Hcur = Hb0; float* Hnxt = Hb1;
  for (int s = 0; s < 8; s++){
    k_gru_gemm<<<dim3(R2/64, 3), 256, 0, stream>>>(idxcat, tokens, embed, BgruT, bsumv,
                                                   bh_map, bh_mem, Hcur, G, Ghn, s);
    k_gru_pointwise<<<(R2*64)/256, 256, 0, stream>>>(G, Ghn, Hcur, Hnxt);
    float* tmp = Hcur; Hcur = Hnxt; Hnxt = tmp;
  }
  k_scatter_h<<<(R2*64)/256, 256, 0, stream>>>(idxcat, Hcur, hA);

  // ---- 2 blocks x (3 plain MP + concat-residual AR MP) ----
  int gb = (N + 63)/64;
  float* cur = hA; float* f1 = hB; float* f2 = hC;
  int li = 0;
  for (int blk = 0; blk < 2; blk++){
    float* saved = cur;
    float* ins[3]  = {cur, f1, f2};
    float* outs[3] = {f1, f2, f1};
    for (int j = 0; j < 3; j++){
      const float* X = ins[j]; float* Yo = outs[j];
      for (int t2 = 0; t2 < 2; t2++){
        gemm3<<<dim3(gb,2), 256, 0, stream>>>(X,70, nullptr,0, nullptr,0,
            Wm_plain + (li*2+t2)*70*70, 70, bm_plain + (li*2+t2)*70,
            (t2 ? P2_1 : P2_0), 70, N, 70, 0);
      }
      k_aggregate<<<(N+3)/4, 256, 0, stream>>>(off, edata, P2_0, P2_1, agg, 70, N);
      gemm3<<<dim3(gb,2), 256, 0, stream>>>(X,70, agg,70, nullptr,0,
          Wu_plain + li*140*70, 70, bu_plain + li*70, Yo, 70, N, 70, 0);
      li++;
    }
    // AR layer: input is concat(saved, f1) [N,140]
    for (int t2 = 0; t2 < 2; t2++){
      gemm3<<<dim3(gb,3), 256, 0, stream>>>(saved,70, f1,70, nullptr,0,
          Wm_ar + (blk*2+t2)*140*140, 140, bm_ar + (blk*2+t2)*140,
          (t2 ? P2_1 : P2_0), 140, N, 140, 1 /*gelu*/);
    }
    k_aggregate<<<(N+3)/4, 256, 0, stream>>>(off, edata, P2_0, P2_1, agg, 140, N);
    gemm3<<<dim3(gb,2), 256, 0, stream>>>(saved,70, f1,70, agg,140,
        Wu_ar + blk*280*70, 70, bu_ar + blk*70, f2, 70, N, 70, 2 /*tanh*/);
    float* t3 = cur; cur = f2; f2 = t3;   // new h in old f2; old saved becomes scratch
  }

  k_head<<<1, 640, 0, stream>>>(cur, entry, W1, b1, W2, b2, out);
}

// Round 2
// 1696.320 us; speedup vs baseline: 2.3593x; 2.3593x over previous
//
#include <hip/hip_runtime.h>
#include <math.h>

#define CAPT 20480              // per-type compacted-node capacity (actual ~16.7k)
#define R2   (2*CAPT)

typedef __attribute__((ext_vector_type(8))) short short8;
typedef __attribute__((ext_vector_type(4))) float f32x4;

__device__ __forceinline__ float sigmoidf_(float x){ return 1.f/(1.f+expf(-x)); }
__device__ __forceinline__ float geluf_(float x){
  const float c = 0.7978845608028654f;
  float t = tanhf(c*(x + 0.044715f*x*x*x));
  return 0.5f*x*(1.f+t);
}
__device__ __forceinline__ unsigned short f2bf(float x){
  unsigned int u = __float_as_uint(x);
  return (unsigned short)((u + 0x7FFFu + ((u>>16)&1u)) >> 16);
}
__device__ __forceinline__ float bf2f(unsigned short v){
  return __uint_as_float(((unsigned int)v) << 16);
}

// ---------------- weight prep: transposed bf16 B arena, padded to 16-mult segments ----
// Arena layout (bf16 elems):
//  [0..6)      plain msg li:  [160][96]   off = li*15360
//  [6..12)     plain upd li:  [80][160]   off = 92160 + li*12800
//  [12..14)    ar msg blk:    [320][160]  off = 168960 + blk*51200
//  [14..16)    ar upd blk:    [80][320]   off = 271360 + blk*25600
//  [16..18)    gru typ:       [256][128]  off = 322560 + typ*32768
__global__ void k_prepB(const float* __restrict__ Wm_plain, const float* __restrict__ Wu_plain,
                        const float* __restrict__ Wm_ar, const float* __restrict__ Wu_ar,
                        const float* __restrict__ Wi_map, const float* __restrict__ Wh_map,
                        const float* __restrict__ Wi_mem, const float* __restrict__ Wh_mem,
                        unsigned short* __restrict__ BtArena){
  int id = blockIdx.y;
  int Kp, elems, off;
  if (id < 6){ Kp=96;  elems=15360; off=id*15360; }
  else if (id < 12){ Kp=160; elems=12800; off=92160+(id-6)*12800; }
  else if (id < 14){ Kp=160; elems=51200; off=168960+(id-12)*51200; }
  else if (id < 16){ Kp=320; elems=25600; off=271360+(id-14)*25600; }
  else { Kp=128; elems=32768; off=322560+(id-16)*32768; }
  for (int g = blockIdx.x*256 + threadIdx.x; g < elems; g += 8*256){
    int c = g / Kp, k = g - c*Kp;
    float val = 0.f;
    if (id < 6){
      int li = id; int t = (c >= 80); int cc = c - t*80;
      if (cc < 70 && k < 70) val = Wm_plain[((li*2+t)*70 + k)*70 + cc];
    } else if (id < 12){
      int li = id-6;
      int kk = (k < 70) ? k : ((k >= 80 && k < 150) ? 70 + (k-80) : -1);
      if (c < 70 && kk >= 0) val = Wu_plain[(li*140 + kk)*70 + c];
    } else if (id < 14){
      int blk = id-12; int t = (c >= 160); int cc = c - t*160;
      int kk = (k < 70) ? k : ((k >= 80 && k < 150) ? 70 + (k-80) : -1);
      if (cc < 140 && kk >= 0) val = Wm_ar[(((blk*2+t)*140) + kk)*140 + cc];
    } else if (id < 16){
      int blk = id-14;
      int kk = (k < 70) ? k : ((k >= 80 && k < 150) ? 70 + (k-80)
               : ((k >= 160 && k < 300) ? 140 + (k-160) : -1));
      if (c < 70 && kk >= 0) val = Wu_ar[(blk*280 + kk)*70 + c];
    } else {
      int typ = id-16;
      const float* Wi = typ ? Wi_mem : Wi_map;
      const float* Wh = typ ? Wh_mem : Wh_map;
      if (c < 192) val = (k < 64) ? Wi[c*64 + k] : Wh[c*64 + (k-64)];
      else { int cc = c-192; val = (k >= 64) ? Wh[(128+cc)*64 + (k-64)] : 0.f; }
    }
    BtArena[off + g] = f2bf(val);
  }
}

// bias arena (fp32): [0..960) plain msg [160]x6; [960..1440) plain upd [80]x6;
// [1440..2080) ar msg [320]x2; [2080..2240) ar upd [80]x2; [2240..2752) gru [256]x2
__global__ void k_prepBias(const float* __restrict__ bm_plain, const float* __restrict__ bu_plain,
                           const float* __restrict__ bm_ar, const float* __restrict__ bu_ar,
                           const float* __restrict__ bi_map, const float* __restrict__ bh_map,
                           const float* __restrict__ bi_mem, const float* __restrict__ bh_mem,
                           float* __restrict__ biasA){
  for (int g = threadIdx.x; g < 2752; g += 256){
    float val = 0.f;
    if (g < 960){ int li=g/160, c=g%160; int t=(c>=80); int cc=c-t*80;
      if (cc<70) val = bm_plain[(li*2+t)*70 + cc]; }
    else if (g < 1440){ int u=g-960; int li=u/80, c=u%80; if (c<70) val = bu_plain[li*70+c]; }
    else if (g < 2080){ int u=g-1440; int blk=u/320, c=u%320; int t=(c>=160); int cc=c-t*160;
      if (cc<140) val = bm_ar[(blk*2+t)*140 + cc]; }
    else if (g < 2240){ int u=g-2080; int blk=u/80, c=u%80; if (c<70) val = bu_ar[blk*70+c]; }
    else { int u=g-2240; int typ=u/256, c=u%256;
      const float* bi = typ ? bi_mem : bi_map; const float* bh = typ ? bh_mem : bh_map;
      val = (c < 192) ? (bi[c]+bh[c]) : bh[128 + (c-192)]; }
    biasA[g] = val;
  }
}

// ---------------- init h = [one_hot(type,6) | zeros] bf16, stride 80 ----------------
__global__ void k_init_h(const int* __restrict__ type_idx, unsigned short* __restrict__ h, int N){
  int g = blockIdx.x*256 + threadIdx.x;
  if (g >= N*80) return;
  int n = g / 80, c = g - n*80;
  h[g] = (c < 6 && type_idx[n] == c) ? (unsigned short)0x3F80 : (unsigned short)0;
}

__global__ void k_compact(const int* __restrict__ type_idx, int* __restrict__ idxcat,
                          int* __restrict__ cnt, int N){
  int n = blockIdx.x*256 + threadIdx.x;
  if (n >= N) return;
  int t = type_idx[n];
  if (t == 0){ int p = atomicAdd(&cnt[0],1); if (p < CAPT) idxcat[p] = n; }
  else if (t == 5){ int p = atomicAdd(&cnt[1],1); if (p < CAPT) idxcat[CAPT+p] = n; }
}

// ---------------- embed gather: Xemb[r][s][k] bf16 ----------------
__global__ void k_xemb(const int* __restrict__ idxcat, const int* __restrict__ tokens,
                       const float* __restrict__ embed, unsigned short* __restrict__ Xemb){
  int g = blockIdx.x*256 + threadIdx.x;
  if (g >= R2*512) return;
  int r = g >> 9, rem = g & 511, s = rem >> 6, k = rem & 63;
  int nd = idxcat[r]; if (nd < 0) nd = 0;
  Xemb[g] = f2bf(embed[tokens[nd*8 + s]*64 + k]);
}

// ---------------- CSR build ----------------
__global__ void k_count(const int* __restrict__ edst, int* __restrict__ deg, int TE){
  int i = blockIdx.x*256 + threadIdx.x;
  if (i < TE) atomicAdd(&deg[edst[i]], 1);
}
__global__ void k_scan1(const int* __restrict__ deg, int* __restrict__ off,
                        int* __restrict__ bsum, int N){
  __shared__ int sh[256];
  int t = threadIdx.x; int base = blockIdx.x*2048;
  int v[8]; int s = 0;
  for (int i=0;i<8;i++){ int g = base + t*8 + i; int x = (g<N)? deg[g] : 0; v[i]=x; s+=x; }
  sh[t]=s; __syncthreads();
  for (int o=1;o<256;o<<=1){ int x = (t>=o)? sh[t-o]:0; __syncthreads(); sh[t]+=x; __syncthreads(); }
  if (t==255) bsum[blockIdx.x] = sh[255];
  int run = sh[t]-s;
  for (int i=0;i<8;i++){ int g = base + t*8 + i; if (g<N) off[g]=run; run+=v[i]; }
}
__global__ void k_scan2(int* bsum, int nb){
  if (threadIdx.x==0 && blockIdx.x==0){ int run=0; for(int b=0;b<nb;b++){ int x=bsum[b]; bsum[b]=run; run+=x; } }
}
__global__ void k_scan3(int* __restrict__ off, const int* __restrict__ bsum, int N, int total){
  int g = blockIdx.x*256+threadIdx.x;
  if (g < N) off[g] += bsum[g>>11];
  if (g == 0) off[N] = total;
}
__global__ void k_fill(const int* __restrict__ esrc, const int* __restrict__ edst,
                       const int* __restrict__ off, int* __restrict__ cur,
                       int* __restrict__ edata, int TE, int E){
  int i = blockIdx.x*256 + threadIdx.x;
  if (i >= TE) return;
  int d = edst[i];
  int pos = off[d] + atomicAdd(&cur[d], 1);
  edata[pos] = (esrc[i] << 1) | (i >= E ? 1 : 0);
}

// ---------------- bf16 MFMA GEMM: C = act([A0|A1|A2] @ B + bias) -----------------
// A segments bf16, widths mult of 16 (pad cols must be zero in the buffers).
// Bt: bf16 [colspad][Kpad] (transposed), zero-padded. Block: 256 rows x NT*16 cols.
template<int NT>
__global__ __launch_bounds__(256) void mgemm(
    const unsigned short* __restrict__ A0, int w0p, int ldA0,
    const unsigned short* __restrict__ A1, int w1p, int ldA1,
    const unsigned short* __restrict__ A2, int w2p, int ldA2,
    const unsigned short* __restrict__ Bt, const unsigned short* __restrict__ Bt2,
    int rowSwitch, int Kpad,
    const float* __restrict__ bias, const float* __restrict__ bias2,
    void* __restrict__ C, int ldC, int rows, int act, int outBf16,
    const int* __restrict__ rowmask)
{
  int rb = blockIdx.x * 256;
  if (rowmask && rowmask[rb] < 0) return;   // fully-pad GRU block
  int cb = blockIdx.y * (NT*16);
  const unsigned short* Bsel = (rb >= rowSwitch) ? Bt2 : Bt;
  const float* bsel = (rb >= rowSwitch) ? bias2 : bias;
  __shared__ __align__(16) unsigned short As[256][32];
  __shared__ __align__(16) unsigned short Bs[NT*16][32];
  int t = threadIdx.x;
  int lane = t & 63, m = lane & 15, quad = lane >> 4;
  int wr = (t >> 6) * 64;
  f32x4 acc[4][NT] = {};
  int KT = Kpad >> 5;
  for (int kt = 0; kt < KT; ++kt){
    int k0 = kt*32;
    for (int u = t; u < 512; u += 256){
      int rowi = u >> 1, half = u & 1;
      int kg = k0 + half*16;
      int gr = rb + rowi;
      uint4 d0 = {0,0,0,0}, d1 = {0,0,0,0};
      if (gr < rows){
        const unsigned short* src = nullptr;
        if (kg < w0p) src = A0 + (size_t)gr*ldA0 + kg;
        else if (kg < w0p + w1p) src = A1 + (size_t)gr*ldA1 + (kg - w0p);
        else if (kg < w0p + w1p + w2p) src = A2 + (size_t)gr*ldA2 + (kg - w0p - w1p);
        if (src){ d0 = *(const uint4*)src; d1 = *(const uint4*)(src + 8); }
      }
      *(uint4*)&As[rowi][half*16]     = d0;
      *(uint4*)&As[rowi][half*16 + 8] = d1;
    }
    if (t < NT*32){
      int c = t >> 1, half = t & 1;
      const unsigned short* sb = Bsel + (size_t)(cb + c)*Kpad + k0 + half*16;
      *(uint4*)&Bs[c][half*16]     = *(const uint4*)sb;
      *(uint4*)&Bs[c][half*16 + 8] = *(const uint4*)(sb + 8);
    }
    __syncthreads();
    short8 af[4];
    #pragma unroll
    for (int rt=0;rt<4;rt++)
      af[rt] = *(const short8*)&As[wr + rt*16 + m][quad*8];
    #pragma unroll
    for (int ct=0;ct<NT;ct++){
      short8 bfr = *(const short8*)&Bs[ct*16 + m][quad*8];
      #pragma unroll
      for (int rt=0;rt<4;rt++)
        acc[rt][ct] = __builtin_amdgcn_mfma_f32_16x16x32_bf16(af[rt], bfr, acc[rt][ct], 0, 0, 0);
    }
    __syncthreads();
  }
  #pragma unroll
  for (int rt=0;rt<4;rt++){
    int baseRow = rb + wr + rt*16 + quad*4;
    #pragma unroll
    for (int ct=0;ct<NT;ct++){
      int gc = cb + ct*16 + m;
      float bv = bsel[gc];
      #pragma unroll
      for (int i=0;i<4;i++){
        int grow = baseRow + i;
        if (grow < rows){
          float v = acc[rt][ct][i] + bv;
          if (act == 1) v = geluf_(v);
          else if (act == 2) v = tanhf(v);
          if (outBf16) ((unsigned short*)C)[(size_t)grow*ldC + gc] = f2bf(v);
          else ((float*)C)[(size_t)grow*ldC + gc] = v;
        }
      }
    }
  }
}

// ---------------- GRU pointwise: h' = (1-z)*n + z*h (G bf16 [r][256]) ----------------
__global__ void k_gru_pointwise(const unsigned short* __restrict__ G,
                                const unsigned short* __restrict__ Hprev,
                                unsigned short* __restrict__ Hnext){
  int g = blockIdx.x*256 + threadIdx.x;     // R2*64 threads
  int row = g >> 6, u = g & 63;
  const unsigned short* Gr = G + (size_t)row*256;
  float r  = sigmoidf_(bf2f(Gr[u]));
  float z  = sigmoidf_(bf2f(Gr[64+u]));
  float hn = bf2f(Gr[192+u]);
  float n  = tanhf(bf2f(Gr[128+u]) + (r - 1.f)*hn);
  float h  = bf2f(Hprev[g]);
  Hnext[g] = f2bf((1.f - z)*n + z*h);
}

__global__ void k_scatter_h(const int* __restrict__ idxcat, const unsigned short* __restrict__ Hlast,
                            unsigned short* __restrict__ h){
  int g = blockIdx.x*256 + threadIdx.x;     // R2*64
  int row = g >> 6, u = g & 63;
  int nd = idxcat[row];
  if (nd >= 0) h[(size_t)nd*80 + 6 + u] = Hlast[g];
}

// ---------------- CSR gather + segment max, bf16, 4-edge unrolled ----------------
__global__ __launch_bounds__(256) void k_aggregate(
    const int* __restrict__ off, const int* __restrict__ edata,
    const unsigned short* __restrict__ P2, int ldP, int off1,
    unsigned short* __restrict__ agg, int ldAgg, int N)
{
  int node = blockIdx.x*4 + (threadIdx.x >> 6);
  int lane = threadIdx.x & 63;
  if (node >= N) return;
  int e0 = off[node], e1 = off[node+1];
  const float NEG = -__builtin_inff();
  float v0 = NEG, v1 = NEG, v2 = NEG;
  int c1 = 64 + lane, c2 = 128 + lane;
  bool a1 = c1 < ldAgg, a2 = c2 < ldAgg;
  int e = e0;
  for (; e + 4 <= e1; e += 4){
    int w0 = edata[e], w1 = edata[e+1], w2 = edata[e+2], w3 = edata[e+3];
    const unsigned short* r0 = P2 + (size_t)(w0>>1)*ldP + (w0&1)*off1;
    const unsigned short* r1 = P2 + (size_t)(w1>>1)*ldP + (w1&1)*off1;
    const unsigned short* r2 = P2 + (size_t)(w2>>1)*ldP + (w2&1)*off1;
    const unsigned short* r3 = P2 + (size_t)(w3>>1)*ldP + (w3&1)*off1;
    float x0 = bf2f(r0[lane]), x1 = bf2f(r1[lane]), x2 = bf2f(r2[lane]), x3 = bf2f(r3[lane]);
    v0 = fmaxf(v0, fmaxf(fmaxf(x0,x1), fmaxf(x2,x3)));
    if (a1){
      float y0 = bf2f(r0[c1]), y1 = bf2f(r1[c1]), y2 = bf2f(r2[c1]), y3 = bf2f(r3[c1]);
      v1 = fmaxf(v1, fmaxf(fmaxf(y0,y1), fmaxf(y2,y3)));
    }
    if (a2){
      float z0 = bf2f(r0[c2]), z1 = bf2f(r1[c2]), z2 = bf2f(r2[c2]), z3 = bf2f(r3[c2]);
      v2 = fmaxf(v2, fmaxf(fmaxf(z0,z1), fmaxf(z2,z3)));
    }
  }
  for (; e < e1; e++){
    int w = edata[e];
    const unsigned short* r0 = P2 + (size_t)(w>>1)*ldP + (w&1)*off1;
    v0 = fmaxf(v0, bf2f(r0[lane]));
    if (a1) v1 = fmaxf(v1, bf2f(r0[c1]));
    if (a2) v2 = fmaxf(v2, bf2f(r0[c2]));
  }
  unsigned short* o = agg + (size_t)node*ldAgg;
  o[lane] = f2bf(v0 == NEG ? 0.f : v0);
  if (a1) o[c1] = f2bf(v1 == NEG ? 0.f : v1);
  if (a2) o[c2] = f2bf(v2 == NEG ? 0.f : v2);
}

// ---------------- final head ----------------
__global__ void k_head(const unsigned short* __restrict__ h, const int* __restrict__ entry,
                       const float* __restrict__ W1, const float* __restrict__ b1,
                       const float* __restrict__ W2, const float* __restrict__ b2,
                       float* __restrict__ out){
  __shared__ float x[70], x1[70];
  int t = threadIdx.x;
  if (t < 70) x[t] = bf2f(h[(size_t)(*entry)*80 + t]);
  __syncthreads();
  if (t < 70){
    float s = b1[t];
    for (int i=0;i<70;i++) s += x[i]*W1[i*70 + t];
    x1[t] = fmaxf(s, 0.f);
  }
  __syncthreads();
  if (t < 640){
    float s = b2[t];
    for (int i=0;i<70;i++) s += x1[i]*W2[i*640 + t];
    out[t] = s;
  }
}

extern "C" void kernel_launch(void* const* d_in, const int* in_sizes, int n_in,
                              void* d_out, int out_size, void* d_ws, size_t ws_size,
                              hipStream_t stream) {
  const int*   tokens   = (const int*)d_in[0];
  const int*   type_idx = (const int*)d_in[1];
  const int*   esrc     = (const int*)d_in[2];
  const int*   edst     = (const int*)d_in[3];
  const int*   entry    = (const int*)d_in[4];
  const float* embed    = (const float*)d_in[5];
  const float* Wi_map   = (const float*)d_in[6];
  const float* Wh_map   = (const float*)d_in[7];
  const float* bi_map   = (const float*)d_in[8];
  const float* bh_map   = (const float*)d_in[9];
  const float* Wi_mem   = (const float*)d_in[10];
  const float* Wh_mem   = (const float*)d_in[11];
  const float* bi_mem   = (const float*)d_in[12];
  const float* bh_mem   = (const float*)d_in[13];
  const float* Wm_plain = (const float*)d_in[14];
  const float* bm_plain = (const float*)d_in[15];
  const float* Wu_plain = (const float*)d_in[16];
  const float* bu_plain = (const float*)d_in[17];
  const float* Wm_ar    = (const float*)d_in[18];
  const float* bm_ar    = (const float*)d_in[19];
  const float* Wu_ar    = (const float*)d_in[20];
  const float* bu_ar    = (const float*)d_in[21];
  const float* W1 = (const float*)d_in[22];
  const float* b1 = (const float*)d_in[23];
  const float* W2 = (const float*)d_in[24];
  const float* b2 = (const float*)d_in[25];
  float* out = (float*)d_out;

  const int N  = in_sizes[1];      // 100000
  const int TE = in_sizes[2];      // 500000
  const int E  = TE / 2;
  const int INTMAX_ = 0x7FFFFFFF;

  char* p = (char*)d_ws;
  auto alloc = [&](size_t bytes)->char* { char* r = p; p += (bytes + 255) & ~(size_t)255; return r; };
  unsigned short* hA  = (unsigned short*)alloc((size_t)N*80*2);
  unsigned short* hB  = (unsigned short*)alloc((size_t)N*80*2);
  unsigned short* hC  = (unsigned short*)alloc((size_t)N*80*2);
  unsigned short* P2  = (unsigned short*)alloc((size_t)N*320*2);   // also Xemb overlay
  unsigned short* agg = (unsigned short*)alloc((size_t)N*160*2);   // also G overlay
  unsigned short* Hb0 = (unsigned short*)alloc((size_t)R2*64*2);
  unsigned short* Hb1 = (unsigned short*)alloc((size_t)R2*64*2);
  int* deg    = (int*)alloc((size_t)N*4);
  int* curp   = (int*)alloc((size_t)N*4);
  int* off    = (int*)alloc((size_t)(N+8)*4);
  int* edata  = (int*)alloc((size_t)TE*4);
  int* sbsum  = (int*)alloc(256*4);
  int* cnt    = (int*)alloc(16*4);
  int* idxcat = (int*)alloc((size_t)R2*4);
  unsigned short* BtA = (unsigned short*)alloc(388096*2);
  float* biasA = (float*)alloc(2752*4);
  unsigned short* Xemb = P2;                   // [R2][512] bf16, dead before P2 is used
  unsigned short* G    = agg;                  // [R2][256] bf16, dead before agg is used

  hipMemsetAsync(idxcat, 0xFF, (size_t)R2*4, stream);
  hipMemsetAsync(cnt,    0,    16*4, stream);
  hipMemsetAsync(deg,    0,    (size_t)N*4, stream);
  hipMemsetAsync(curp,   0,    (size_t)N*4, stream);
  hipMemsetAsync(Hb0,    0,    (size_t)R2*64*2, stream);

  k_prepB<<<dim3(8,18), 256, 0, stream>>>(Wm_plain, Wu_plain, Wm_ar, Wu_ar,
                                          Wi_map, Wh_map, Wi_mem, Wh_mem, BtA);
  k_prepBias<<<1, 256, 0, stream>>>(bm_plain, bu_plain, bm_ar, bu_ar,
                                    bi_map, bh_map, bi_mem, bh_mem, biasA);
  k_init_h<<<(N*80+255)/256, 256, 0, stream>>>(type_idx, hA, N);
  k_compact<<<(N+255)/256, 256, 0, stream>>>(type_idx, idxcat, cnt, N);

  k_count<<<(TE+255)/256, 256, 0, stream>>>(edst, deg, TE);
  int nb = (N + 2047)/2048;
  k_scan1<<<nb, 256, 0, stream>>>(deg, off, sbsum, N);
  k_scan2<<<1, 64, 0, stream>>>(sbsum, nb);
  k_scan3<<<(N+255)/256, 256, 0, stream>>>(off, sbsum, N, TE);
  k_fill<<<(TE+255)/256, 256, 0, stream>>>(esrc, edst, off, curp, edata, TE, E);

  k_xemb<<<(R2*512)/256, 256, 0, stream>>>(idxcat, tokens, embed, Xemb);

  // ---- GRU: 8 steps ----
  const unsigned short* BtG0 = BtA + 322560;
  const unsigned short* BtG1 = BtA + 322560 + 32768;
  const float* bG0 = biasA + 2240;
  const float* bG1 = biasA + 2240 + 256;
  unsigned short* Hcur = Hb0; unsigned short* Hnxt = Hb1;
  for (int s = 0; s < 8; s++){
    mgemm<4><<<dim3(R2/256, 4), 256, 0, stream>>>(
        Xemb + s*64, 64, 512,  Hcur, 64, 64,  nullptr, 0, 0,
        BtG0, BtG1, CAPT, 128, bG0, bG1,
        (void*)G, 256, R2, 0, 1, idxcat);
    k_gru_pointwise<<<(R2*64)/256, 256, 0, stream>>>(G, Hcur, Hnxt);
    unsigned short* tmp = Hcur; Hcur = Hnxt; Hnxt = tmp;
  }
  k_scatter_h<<<(R2*64)/256, 256, 0, stream>>>(idxcat, Hcur, hA);

  // ---- 2 blocks x (3 plain MP + concat-residual AR MP) ----
  int GX = (N + 255)/256;
  unsigned short* cur = hA; unsigned short* f1 = hB; unsigned short* f2 = hC;
  int li = 0;
  for (int blk = 0; blk < 2; blk++){
    unsigned short* saved = cur;
    unsigned short* ins[3]  = {cur, f1, f2};
    unsigned short* outs[3] = {f1, f2, f1};
    for (int j = 0; j < 3; j++){
      unsigned short* X = ins[j]; unsigned short* Yo = outs[j];
      mgemm<5><<<dim3(GX, 2), 256, 0, stream>>>(
          X, 80, 80,  nullptr, 0, 0,  nullptr, 0, 0,
          BtA + li*15360, BtA, INTMAX_, 96, biasA + li*160, biasA,
          (void*)P2, 160, N, 0, 1, nullptr);
      k_aggregate<<<(N+3)/4, 256, 0, stream>>>(off, edata, P2, 160, 80, agg, 80, N);
      mgemm<5><<<dim3(GX, 1), 256, 0, stream>>>(
          X, 80, 80,  agg, 80, 80,  nullptr, 0, 0,
          BtA + 92160 + li*12800, BtA, INTMAX_, 160, biasA + 960 + li*80, biasA,
          (void*)Yo, 80, N, 0, 1, nullptr);
      li++;
    }
    mgemm<5><<<dim3(GX, 4), 256, 0, stream>>>(
        saved, 80, 80,  f1, 80, 80,  nullptr, 0, 0,
        BtA + 168960 + blk*51200, BtA, INTMAX_, 160, biasA + 1440 + blk*320, biasA,
        (void*)P2, 320, N, 1 /*gelu*/, 1, nullptr);
    k_aggregate<<<(N+3)/4, 256, 0, stream>>>(off, edata, P2, 320, 160, agg, 160, N);
    mgemm<5><<<dim3(GX, 1), 256, 0, stream>>>(
        saved, 80, 80,  f1, 80, 80,  agg, 160, 160,
        BtA + 271360 + blk*25600, BtA, INTMAX_, 320, biasA + 2080 + blk*80, biasA,
        (void*)f2, 80, N, 2 /*tanh*/, 1, nullptr);
    unsigned short* t3 = cur; cur = f2; f2 = t3;
  }

  k_head<<<1, 640, 0, stream>>>(cur, entry, W1, b1, W2, b2, out);
}

// Round 3
// 1373.967 us; speedup vs baseline: 2.9128x; 1.2346x over previous
//
#include <hip/hip_runtime.h>
#include <math.h>

#define CAPT 20480              // per-type compacted-node capacity (actual ~16.7k)
#define R2   (2*CAPT)

typedef __attribute__((ext_vector_type(8))) short short8;
typedef __attribute__((ext_vector_type(4))) float f32x4;

__device__ __forceinline__ float sigmoidf_(float x){ return 1.f/(1.f+expf(-x)); }
__device__ __forceinline__ float geluf_(float x){
  const float c = 0.7978845608028654f;
  float t = tanhf(c*(x + 0.044715f*x*x*x));
  return 0.5f*x*(1.f+t);
}
__device__ __forceinline__ unsigned short f2bf(float x){
  unsigned int u = __float_as_uint(x);
  return (unsigned short)((u + 0x7FFFu + ((u>>16)&1u)) >> 16);
}
__device__ __forceinline__ float bf2f(unsigned short v){
  return __uint_as_float(((unsigned int)v) << 16);
}

// ---------------- weight prep: transposed bf16 B arena, padded to 16-mult segments ----
// Arena layout (bf16 elems):
//  [0..6)      plain msg li:  [160][96]   off = li*15360
//  [6..12)     plain upd li:  [80][160]   off = 92160 + li*12800
//  [12..14)    ar msg blk:    [320][160]  off = 168960 + blk*51200
//  [14..16)    ar upd blk:    [80][320]   off = 271360 + blk*25600
//  [16..18)    gru typ:       [256][128]  off = 322560 + typ*32768
__global__ void k_prepB(const float* __restrict__ Wm_plain, const float* __restrict__ Wu_plain,
                        const float* __restrict__ Wm_ar, const float* __restrict__ Wu_ar,
                        const float* __restrict__ Wi_map, const float* __restrict__ Wh_map,
                        const float* __restrict__ Wi_mem, const float* __restrict__ Wh_mem,
                        unsigned short* __restrict__ BtArena){
  int id = blockIdx.y;
  int Kp, elems, off;
  if (id < 6){ Kp=96;  elems=15360; off=id*15360; }
  else if (id < 12){ Kp=160; elems=12800; off=92160+(id-6)*12800; }
  else if (id < 14){ Kp=160; elems=51200; off=168960+(id-12)*51200; }
  else if (id < 16){ Kp=320; elems=25600; off=271360+(id-14)*25600; }
  else { Kp=128; elems=32768; off=322560+(id-16)*32768; }
  for (int g = blockIdx.x*256 + threadIdx.x; g < elems; g += 8*256){
    int c = g / Kp, k = g - c*Kp;
    float val = 0.f;
    if (id < 6){
      int li = id; int t = (c >= 80); int cc = c - t*80;
      if (cc < 70 && k < 70) val = Wm_plain[((li*2+t)*70 + k)*70 + cc];
    } else if (id < 12){
      int li = id-6;
      int kk = (k < 70) ? k : ((k >= 80 && k < 150) ? 70 + (k-80) : -1);
      if (c < 70 && kk >= 0) val = Wu_plain[(li*140 + kk)*70 + c];
    } else if (id < 14){
      int blk = id-12; int t = (c >= 160); int cc = c - t*160;
      int kk = (k < 70) ? k : ((k >= 80 && k < 150) ? 70 + (k-80) : -1);
      if (cc < 140 && kk >= 0) val = Wm_ar[(((blk*2+t)*140) + kk)*140 + cc];
    } else if (id < 16){
      int blk = id-14;
      int kk = (k < 70) ? k : ((k >= 80 && k < 150) ? 70 + (k-80)
               : ((k >= 160 && k < 300) ? 140 + (k-160) : -1));
      if (c < 70 && kk >= 0) val = Wu_ar[(blk*280 + kk)*70 + c];
    } else {
      int typ = id-16;
      const float* Wi = typ ? Wi_mem : Wi_map;
      const float* Wh = typ ? Wh_mem : Wh_map;
      if (c < 192) val = (k < 64) ? Wi[c*64 + k] : Wh[c*64 + (k-64)];
      else { int cc = c-192; val = (k >= 64) ? Wh[(128+cc)*64 + (k-64)] : 0.f; }
    }
    BtArena[off + g] = f2bf(val);
  }
}

// bias arena (fp32): [0..960) plain msg [160]x6; [960..1440) plain upd [80]x6;
// [1440..2080) ar msg [320]x2; [2080..2240) ar upd [80]x2; [2240..2752) gru [256]x2
__global__ void k_prepBias(const float* __restrict__ bm_plain, const float* __restrict__ bu_plain,
                           const float* __restrict__ bm_ar, const float* __restrict__ bu_ar,
                           const float* __restrict__ bi_map, const float* __restrict__ bh_map,
                           const float* __restrict__ bi_mem, const float* __restrict__ bh_mem,
                           float* __restrict__ biasA){
  for (int g = threadIdx.x; g < 2752; g += 256){
    float val = 0.f;
    if (g < 960){ int li=g/160, c=g%160; int t=(c>=80); int cc=c-t*80;
      if (cc<70) val = bm_plain[(li*2+t)*70 + cc]; }
    else if (g < 1440){ int u=g-960; int li=u/80, c=u%80; if (c<70) val = bu_plain[li*70+c]; }
    else if (g < 2080){ int u=g-1440; int blk=u/320, c=u%320; int t=(c>=160); int cc=c-t*160;
      if (cc<140) val = bm_ar[(blk*2+t)*140 + cc]; }
    else if (g < 2240){ int u=g-2080; int blk=u/80, c=u%80; if (c<70) val = bu_ar[blk*70+c]; }
    else { int u=g-2240; int typ=u/256, c=u%256;
      const float* bi = typ ? bi_mem : bi_map; const float* bh = typ ? bh_mem : bh_map;
      val = (c < 192) ? (bi[c]+bh[c]) : bh[128 + (c-192)]; }
    biasA[g] = val;
  }
}

// ---------------- init h = [one_hot(type,6) | zeros] bf16, stride 80 ----------------
__global__ void k_init_h(const int* __restrict__ type_idx, unsigned short* __restrict__ h, int N){
  int g = blockIdx.x*256 + threadIdx.x;
  if (g >= N*80) return;
  int n = g / 80, c = g - n*80;
  h[g] = (c < 6 && type_idx[n] == c) ? (unsigned short)0x3F80 : (unsigned short)0;
}

__global__ void k_compact(const int* __restrict__ type_idx, int* __restrict__ idxcat,
                          int* __restrict__ cnt, int N){
  int n = blockIdx.x*256 + threadIdx.x;
  if (n >= N) return;
  int t = type_idx[n];
  if (t == 0){ int p = atomicAdd(&cnt[0],1); if (p < CAPT) idxcat[p] = n; }
  else if (t == 5){ int p = atomicAdd(&cnt[1],1); if (p < CAPT) idxcat[CAPT+p] = n; }
}

// ---------------- embed gather: Xemb[r][s][k] bf16 ----------------
__global__ void k_xemb(const int* __restrict__ idxcat, const int* __restrict__ tokens,
                       const float* __restrict__ embed, unsigned short* __restrict__ Xemb){
  int g = blockIdx.x*256 + threadIdx.x;
  if (g >= R2*512) return;
  int r = g >> 9, rem = g & 511, s = rem >> 6, k = rem & 63;
  int nd = idxcat[r]; if (nd < 0) nd = 0;
  Xemb[g] = f2bf(embed[tokens[nd*8 + s]*64 + k]);
}

// ---------------- CSR build ----------------
__global__ void k_count(const int* __restrict__ edst, int* __restrict__ deg, int TE){
  int i = blockIdx.x*256 + threadIdx.x;
  if (i < TE) atomicAdd(&deg[edst[i]], 1);
}
__global__ void k_scan1(const int* __restrict__ deg, int* __restrict__ off,
                        int* __restrict__ bsum, int N){
  __shared__ int sh[256];
  int t = threadIdx.x; int base = blockIdx.x*2048;
  int v[8]; int s = 0;
  for (int i=0;i<8;i++){ int g = base + t*8 + i; int x = (g<N)? deg[g] : 0; v[i]=x; s+=x; }
  sh[t]=s; __syncthreads();
  for (int o=1;o<256;o<<=1){ int x = (t>=o)? sh[t-o]:0; __syncthreads(); sh[t]+=x; __syncthreads(); }
  if (t==255) bsum[blockIdx.x] = sh[255];
  int run = sh[t]-s;
  for (int i=0;i<8;i++){ int g = base + t*8 + i; if (g<N) off[g]=run; run+=v[i]; }
}
__global__ void k_scan2(int* bsum, int nb){
  if (threadIdx.x==0 && blockIdx.x==0){ int run=0; for(int b=0;b<nb;b++){ int x=bsum[b]; bsum[b]=run; run+=x; } }
}
__global__ void k_scan3(int* __restrict__ off, const int* __restrict__ bsum, int N, int total){
  int g = blockIdx.x*256+threadIdx.x;
  if (g < N) off[g] += bsum[g>>11];
  if (g == 0) off[N] = total;
}
__global__ void k_fill(const int* __restrict__ esrc, const int* __restrict__ edst,
                       const int* __restrict__ off, int* __restrict__ cur,
                       int* __restrict__ edata, int TE, int E){
  int i = blockIdx.x*256 + threadIdx.x;
  if (i >= TE) return;
  int d = edst[i];
  int pos = off[d] + atomicAdd(&cur[d], 1);
  edata[pos] = (esrc[i] << 1) | (i >= E ? 1 : 0);
}

// ======== wgemm: B-in-registers MFMA GEMM =========================================
// C = act([A0|A1|A2] @ B + bias), A bf16 segment widths mult of 16 shorts.
// Bt arena: [colspad][KpB] bf16 transposed, zero-padded.
// Block = 4 waves; wave w owns col tiles {tileBase + w + 4j, j<CT} (16 cols each).
// Row tiles of RTR rows; whole K staged in LDS, double-buffered, ONE barrier/tile:
//   loadRegs(next) -> barrier -> mfma(buf p) + store C -> ds_write(next -> buf p^1).
// mode 0: blockIdx.y = col group (tileBase = y*4*CT). mode 1 (GRU): blockIdx.y = row
// region (y*CAPT), B/bias selected per region, row loop clamped by cnt[y].
template<int RTR, int KT, int CT>
__global__ __launch_bounds__(256) void wgemm(
    const unsigned short* __restrict__ A0, int w0, int ldA0,
    const unsigned short* __restrict__ A1, int w1, int ldA1,
    const unsigned short* __restrict__ A2, int w2, int ldA2,
    const unsigned short* __restrict__ Bt, const unsigned short* __restrict__ Bt2, int KpB,
    const float* __restrict__ bias, const float* __restrict__ bias2,
    unsigned short* __restrict__ C, int ldC,
    int rows, int tiles, int act, int mode, const int* __restrict__ cnt)
{
  constexpr int Kpad = KT*32;
  constexpr int NRT  = RTR/16;
  constexpr int CPT  = (RTR*Kpad/8)/256;   // 16B chunks per thread per tile
  __shared__ __align__(16) unsigned short As[2][RTR*Kpad];
  int t = threadIdx.x;
  int lane = t & 63, m = lane & 15, q = lane >> 4, w = t >> 6;
  int rowBase = 0, tileBase = 0, rtEnd;
  const unsigned short* Bsel = Bt; const float* bsel = bias;
  if (mode == 1){
    rowBase = blockIdx.y * CAPT;
    int c = cnt[blockIdx.y]; if (c > CAPT) c = CAPT;
    rtEnd = (c + RTR - 1)/RTR;
    if (blockIdx.y == 1){ Bsel = Bt2; bsel = bias2; }
  } else {
    tileBase = blockIdx.y * (4*CT);
    rtEnd = (rows + RTR - 1)/RTR;
  }
  int tr = blockIdx.x;
  if (tr >= rtEnd) return;

  // ---- B fragments + bias into registers, once per block ----
  short8 breg[CT][KT]; float bv[CT]; bool val[CT]; int colr[CT];
  #pragma unroll
  for (int j=0;j<CT;j++){
    int tt = tileBase + w + 4*j;
    val[j] = (tt < tiles);
    int col = tt*16 + m;
    colr[j] = col;
    bv[j] = 0.f;
    if (val[j]){
      bv[j] = bsel[col];
      #pragma unroll
      for (int kt=0;kt<KT;kt++)
        breg[j][kt] = *(const short8*)&Bsel[(size_t)col*KpB + kt*32 + q*8];
    } else {
      #pragma unroll
      for (int kt=0;kt<KT;kt++) breg[j][kt] = (short8){0,0,0,0,0,0,0,0};
    }
  }

  int w01 = w0 + w1, w012 = w0 + w1 + w2;
  uint4 r[CPT];
  auto loadRegs = [&](int trr){
    #pragma unroll
    for (int i=0;i<CPT;i++){
      int c = i*256 + t;
      int row = c / (KT*4), kc = (c - row*(KT*4))*8;
      int gr = rowBase + trr*RTR + row;
      uint4 v = {0,0,0,0};
      if (gr < rows && kc < w012){
        const unsigned short* sp;
        if (kc < w0)       sp = A0 + (size_t)gr*ldA0 + kc;
        else if (kc < w01) sp = A1 + (size_t)gr*ldA1 + (kc - w0);
        else               sp = A2 + (size_t)gr*ldA2 + (kc - w01);
        v = *(const uint4*)sp;
      }
      r[i] = v;
    }
  };
  auto dsw = [&](int p){
    #pragma unroll
    for (int i=0;i<CPT;i++){
      int c = i*256 + t;
      int row = c / (KT*4), kc = (c - row*(KT*4))*8;
      *(uint4*)&As[p][row*Kpad + kc] = r[i];
    }
  };

  loadRegs(tr);
  dsw(0);
  int p = 0;
  for (;;){
    int nxt = tr + gridDim.x;
    bool hasNext = (nxt < rtEnd);
    if (hasNext) loadRegs(nxt);      // global loads in flight across the barrier
    __syncthreads();                 // buf[p] ready; prior reads of buf[p^1] done
    f32x4 acc[NRT][CT] = {};
    #pragma unroll
    for (int kt=0;kt<KT;kt++){
      short8 af[NRT];
      #pragma unroll
      for (int rt=0;rt<NRT;rt++)
        af[rt] = *(const short8*)&As[p][(rt*16+m)*Kpad + kt*32 + q*8];
      #pragma unroll
      for (int j=0;j<CT;j++)
        #pragma unroll
        for (int rt=0;rt<NRT;rt++)
          acc[rt][j] = __builtin_amdgcn_mfma_f32_16x16x32_bf16(af[rt], breg[j][kt], acc[rt][j], 0,0,0);
    }
    #pragma unroll
    for (int rt=0;rt<NRT;rt++){
      int rbase = rowBase + tr*RTR + rt*16 + q*4;
      #pragma unroll
      for (int j=0;j<CT;j++){
        if (!val[j]) continue;
        #pragma unroll
        for (int i=0;i<4;i++){
          int grow = rbase + i;
          if (grow < rows){
            float v = acc[rt][j][i] + bv[j];
            if (act == 1) v = geluf_(v);
            else if (act == 2) v = tanhf(v);
            C[(size_t)grow*ldC + colr[j]] = f2bf(v);
          }
        }
      }
    }
    if (!hasNext) break;
    dsw(p^1);                        // safe: all reads of buf[p^1] were pre-barrier
    p ^= 1; tr = nxt;
  }
}

// ---------------- GRU pointwise: h' = (1-z)*n + z*h (G bf16 [r][256]) ----------------
__global__ void k_gru_pointwise(const unsigned short* __restrict__ G,
                                const unsigned short* __restrict__ Hprev,
                                unsigned short* __restrict__ Hnext){
  int g = blockIdx.x*256 + threadIdx.x;     // R2*64 threads
  int row = g >> 6, u = g & 63;
  const unsigned short* Gr = G + (size_t)row*256;
  float r  = sigmoidf_(bf2f(Gr[u]));
  float z  = sigmoidf_(bf2f(Gr[64+u]));
  float hn = bf2f(Gr[192+u]);
  float n  = tanhf(bf2f(Gr[128+u]) + (r - 1.f)*hn);
  float h  = bf2f(Hprev[g]);
  Hnext[g] = f2bf((1.f - z)*n + z*h);
}

__global__ void k_scatter_h(const int* __restrict__ idxcat, const unsigned short* __restrict__ Hlast,
                            unsigned short* __restrict__ h){
  int g = blockIdx.x*256 + threadIdx.x;     // R2*64
  int row = g >> 6, u = g & 63;
  int nd = idxcat[row];
  if (nd >= 0) h[(size_t)nd*80 + 6 + u] = Hlast[g];
}

// ---------------- CSR gather + segment max, bf16, 4-edge unrolled ----------------
__global__ __launch_bounds__(256) void k_aggregate(
    const int* __restrict__ off, const int* __restrict__ edata,
    const unsigned short* __restrict__ P2, int ldP, int off1,
    unsigned short* __restrict__ agg, int ldAgg, int N)
{
  int node = blockIdx.x*4 + (threadIdx.x >> 6);
  int lane = threadIdx.x & 63;
  if (node >= N) return;
  int e0 = off[node], e1 = off[node+1];
  const float NEG = -__builtin_inff();
  float v0 = NEG, v1 = NEG, v2 = NEG;
  int c1 = 64 + lane, c2 = 128 + lane;
  bool a1 = c1 < ldAgg, a2 = c2 < ldAgg;
  int e = e0;
  for (; e + 4 <= e1; e += 4){
    int w0 = edata[e], w1 = edata[e+1], w2 = edata[e+2], w3 = edata[e+3];
    const unsigned short* r0 = P2 + (size_t)(w0>>1)*ldP + (w0&1)*off1;
    const unsigned short* r1 = P2 + (size_t)(w1>>1)*ldP + (w1&1)*off1;
    const unsigned short* r2 = P2 + (size_t)(w2>>1)*ldP + (w2&1)*off1;
    const unsigned short* r3 = P2 + (size_t)(w3>>1)*ldP + (w3&1)*off1;
    float x0 = bf2f(r0[lane]), x1 = bf2f(r1[lane]), x2 = bf2f(r2[lane]), x3 = bf2f(r3[lane]);
    v0 = fmaxf(v0, fmaxf(fmaxf(x0,x1), fmaxf(x2,x3)));
    if (a1){
      float y0 = bf2f(r0[c1]), y1 = bf2f(r1[c1]), y2 = bf2f(r2[c1]), y3 = bf2f(r3[c1]);
      v1 = fmaxf(v1, fmaxf(fmaxf(y0,y1), fmaxf(y2,y3)));
    }
    if (a2){
      float z0 = bf2f(r0[c2]), z1 = bf2f(r1[c2]), z2 = bf2f(r2[c2]), z3 = bf2f(r3[c2]);
      v2 = fmaxf(v2, fmaxf(fmaxf(z0,z1), fmaxf(z2,z3)));
    }
  }
  for (; e < e1; e++){
    int w = edata[e];
    const unsigned short* r0 = P2 + (size_t)(w>>1)*ldP + (w&1)*off1;
    v0 = fmaxf(v0, bf2f(r0[lane]));
    if (a1) v1 = fmaxf(v1, bf2f(r0[c1]));
    if (a2) v2 = fmaxf(v2, bf2f(r0[c2]));
  }
  unsigned short* o = agg + (size_t)node*ldAgg;
  o[lane] = f2bf(v0 == NEG ? 0.f : v0);
  if (a1) o[c1] = f2bf(v1 == NEG ? 0.f : v1);
  if (a2) o[c2] = f2bf(v2 == NEG ? 0.f : v2);
}

// ---------------- final head ----------------
__global__ void k_head(const unsigned short* __restrict__ h, const int* __restrict__ entry,
                       const float* __restrict__ W1, const float* __restrict__ b1,
                       const float* __restrict__ W2, const float* __restrict__ b2,
                       float* __restrict__ out){
  __shared__ float x[70], x1[70];
  int t = threadIdx.x;
  if (t < 70) x[t] = bf2f(h[(size_t)(*entry)*80 + t]);
  __syncthreads();
  if (t < 70){
    float s = b1[t];
    for (int i=0;i<70;i++) s += x[i]*W1[i*70 + t];
    x1[t] = fmaxf(s, 0.f);
  }
  __syncthreads();
  if (t < 640){
    float s = b2[t];
    for (int i=0;i<70;i++) s += x1[i]*W2[i*640 + t];
    out[t] = s;
  }
}

extern "C" void kernel_launch(void* const* d_in, const int* in_sizes, int n_in,
                              void* d_out, int out_size, void* d_ws, size_t ws_size,
                              hipStream_t stream) {
  const int*   tokens   = (const int*)d_in[0];
  const int*   type_idx = (const int*)d_in[1];
  const int*   esrc     = (const int*)d_in[2];
  const int*   edst     = (const int*)d_in[3];
  const int*   entry    = (const int*)d_in[4];
  const float* embed    = (const float*)d_in[5];
  const float* Wi_map   = (const float*)d_in[6];
  const float* Wh_map   = (const float*)d_in[7];
  const float* bi_map   = (const float*)d_in[8];
  const float* bh_map   = (const float*)d_in[9];
  const float* Wi_mem   = (const float*)d_in[10];
  const float* Wh_mem   = (const float*)d_in[11];
  const float* bi_mem   = (const float*)d_in[12];
  const float* bh_mem   = (const float*)d_in[13];
  const float* Wm_plain = (const float*)d_in[14];
  const float* bm_plain = (const float*)d_in[15];
  const float* Wu_plain = (const float*)d_in[16];
  const float* bu_plain = (const float*)d_in[17];
  const float* Wm_ar    = (const float*)d_in[18];
  const float* bm_ar    = (const float*)d_in[19];
  const float* Wu_ar    = (const float*)d_in[20];
  const float* bu_ar    = (const float*)d_in[21];
  const float* W1 = (const float*)d_in[22];
  const float* b1 = (const float*)d_in[23];
  const float* W2 = (const float*)d_in[24];
  const float* b2 = (const float*)d_in[25];
  float* out = (float*)d_out;

  const int N  = in_sizes[1];      // 100000
  const int TE = in_sizes[2];      // 500000
  const int E  = TE / 2;

  char* p = (char*)d_ws;
  auto alloc = [&](size_t bytes)->char* { char* r = p; p += (bytes + 255) & ~(size_t)255; return r; };
  unsigned short* hA  = (unsigned short*)alloc((size_t)N*80*2);
  unsigned short* hB  = (unsigned short*)alloc((size_t)N*80*2);
  unsigned short* hC  = (unsigned short*)alloc((size_t)N*80*2);
  unsigned short* P2  = (unsigned short*)alloc((size_t)N*320*2);   // also Xemb overlay
  unsigned short* agg = (unsigned short*)alloc((size_t)N*160*2);   // also G overlay
  unsigned short* Hb0 = (unsigned short*)alloc((size_t)R2*64*2);
  unsigned short* Hb1 = (unsigned short*)alloc((size_t)R2*64*2);
  int* deg    = (int*)alloc((size_t)N*4);
  int* curp   = (int*)alloc((size_t)N*4);
  int* off    = (int*)alloc((size_t)(N+8)*4);
  int* edata  = (int*)alloc((size_t)TE*4);
  int* sbsum  = (int*)alloc(256*4);
  int* cnt    = (int*)alloc(16*4);
  int* idxcat = (int*)alloc((size_t)R2*4);
  unsigned short* BtA = (unsigned short*)alloc(388096*2);
  float* biasA = (float*)alloc(2752*4);
  unsigned short* Xemb = P2;                   // [R2][512] bf16, dead before P2 is used
  unsigned short* G    = agg;                  // [R2][256] bf16, dead before agg is used

  hipMemsetAsync(idxcat, 0xFF, (size_t)R2*4, stream);
  hipMemsetAsync(cnt,    0,    16*4, stream);
  hipMemsetAsync(deg,    0,    (size_t)N*4, stream);
  hipMemsetAsync(curp,   0,    (size_t)N*4, stream);
  hipMemsetAsync(Hb0,    0,    (size_t)R2*64*2, stream);

  k_prepB<<<dim3(8,18), 256, 0, stream>>>(Wm_plain, Wu_plain, Wm_ar, Wu_ar,
                                          Wi_map, Wh_map, Wi_mem, Wh_mem, BtA);
  k_prepBias<<<1, 256, 0, stream>>>(bm_plain, bu_plain, bm_ar, bu_ar,
                                    bi_map, bh_map, bi_mem, bh_mem, biasA);
  k_init_h<<<(N*80+255)/256, 256, 0, stream>>>(type_idx, hA, N);
  k_compact<<<(N+255)/256, 256, 0, stream>>>(type_idx, idxcat, cnt, N);

  k_count<<<(TE+255)/256, 256, 0, stream>>>(edst, deg, TE);
  int nb = (N + 2047)/2048;
  k_scan1<<<nb, 256, 0, stream>>>(deg, off, sbsum, N);
  k_scan2<<<1, 64, 0, stream>>>(sbsum, nb);
  k_scan3<<<(N+255)/256, 256, 0, stream>>>(off, sbsum, N, TE);
  k_fill<<<(TE+255)/256, 256, 0, stream>>>(esrc, edst, off, curp, edata, TE, E);

  k_xemb<<<(R2*512)/256, 256, 0, stream>>>(idxcat, tokens, embed, Xemb);

  // ---- GRU: 8 steps; y = type region, row loop clamped by cnt[y] ----
  const unsigned short* BtG0 = BtA + 322560;
  const unsigned short* BtG1 = BtA + 322560 + 32768;
  const float* bG0 = biasA + 2240;
  const float* bG1 = biasA + 2240 + 256;
  unsigned short* Hcur = Hb0; unsigned short* Hnxt = Hb1;
  for (int s = 0; s < 8; s++){
    wgemm<64,4,4><<<dim3(CAPT/64, 2), 256, 0, stream>>>(
        Xemb + s*64, 64, 512,  Hcur, 64, 64,  nullptr, 0, 0,
        BtG0, BtG1, 128, bG0, bG1,
        G, 256, R2, 16, 0, 1, cnt);
    k_gru_pointwise<<<(R2*64)/256, 256, 0, stream>>>(G, Hcur, Hnxt);
    unsigned short* tmp = Hcur; Hcur = Hnxt; Hnxt = tmp;
  }
  k_scatter_h<<<(R2*64)/256, 256, 0, stream>>>(idxcat, Hcur, hA);

  // ---- 2 blocks x (3 plain MP + concat-residual AR MP) ----
  unsigned short* cur = hA; unsigned short* f1 = hB; unsigned short* f2 = hC;
  int li = 0;
  for (int blk = 0; blk < 2; blk++){
    unsigned short* saved = cur;
    unsigned short* ins[3]  = {cur, f1, f2};
    unsigned short* outs[3] = {f1, f2, f1};
    for (int j = 0; j < 3; j++){
      unsigned short* X = ins[j]; unsigned short* Yo = outs[j];
      // msg: [N,80] @ [96->160] (both edge types fused in cols)
      wgemm<64,3,3><<<dim3(1024,1), 256, 0, stream>>>(
          X, 80, 80,  nullptr, 0, 0,  nullptr, 0, 0,
          BtA + li*15360, nullptr, 96, biasA + li*160, nullptr,
          P2, 160, N, 10, 0, 0, nullptr);
      k_aggregate<<<(N+3)/4, 256, 0, stream>>>(off, edata, P2, 160, 80, agg, 80, N);
      // upd: [N,80|80] @ [160->80]
      wgemm<64,5,2><<<dim3(1024,1), 256, 0, stream>>>(
          X, 80, 80,  agg, 80, 80,  nullptr, 0, 0,
          BtA + 92160 + li*12800, nullptr, 160, biasA + 960 + li*80, nullptr,
          Yo, 80, N, 5, 0, 0, nullptr);
      li++;
    }
    // AR msg: [N,80|80] @ [160->320], gelu; y splits 20 col tiles into 12+8
    wgemm<64,5,3><<<dim3(512,2), 256, 0, stream>>>(
        saved, 80, 80,  f1, 80, 80,  nullptr, 0, 0,
        BtA + 168960 + blk*51200, nullptr, 160, biasA + 1440 + blk*320, nullptr,
        P2, 320, N, 20, 1 /*gelu*/, 0, nullptr);
    k_aggregate<<<(N+3)/4, 256, 0, stream>>>(off, edata, P2, 320, 160, agg, 160, N);
    // AR upd: [N,80|80|160] @ [320->80], tanh; 32-row tiles (K=320 LDS)
    wgemm<32,10,2><<<dim3(1024,1), 256, 0, stream>>>(
        saved, 80, 80,  f1, 80, 80,  agg, 160, 160,
        BtA + 271360 + blk*25600, nullptr, 320, biasA + 2080 + blk*80, nullptr,
        f2, 80, N, 5, 2 /*tanh*/, 0, nullptr);
    unsigned short* t3 = cur; cur = f2; f2 = t3;
  }

  k_head<<<1, 640, 0, stream>>>(cur, entry, W1, b1, W2, b2, out);
}

// Round 4
// 1143.614 us; speedup vs baseline: 3.4995x; 1.2014x over previous
//
#include <hip/hip_runtime.h>
#include <math.h>

#define CAPT 20480              // per-type compacted-node capacity (actual ~16.7k)
#define R2   (2*CAPT)

typedef __attribute__((ext_vector_type(8))) short short8;
typedef __attribute__((ext_vector_type(4))) float f32x4;

// ---- fast transcendentals: v_exp_f32 / v_rcp_f32 based; err ~1e-7 << bf16 ulp ----
__device__ __forceinline__ float fexp2_(float x){ return __builtin_amdgcn_exp2f(x); }
__device__ __forceinline__ float frcp_(float x){ return __builtin_amdgcn_rcpf(x); }
__device__ __forceinline__ float ftanh_(float x){
  float ax = __builtin_fabsf(x);
  float t = fexp2_(-2.885390082f * ax);          // e^{-2|x|}
  float r = (1.f - t) * frcp_(1.f + t);
  return __builtin_copysignf(r, x);
}
__device__ __forceinline__ float fsig_(float x){
  return frcp_(1.f + fexp2_(-1.442695041f * x));
}
__device__ __forceinline__ float fgelu_(float x){
  const float c = 0.7978845608028654f;
  return 0.5f*x*(1.f + ftanh_(c*(x + 0.044715f*x*x*x)));
}
__device__ __forceinline__ unsigned short f2bf(float x){
  unsigned int u = __float_as_uint(x);
  return (unsigned short)((u + 0x7FFFu + ((u>>16)&1u)) >> 16);
}
__device__ __forceinline__ float bf2f(unsigned short v){
  return __uint_as_float(((unsigned int)v) << 16);
}

// ---------------- weight prep: transposed bf16 B arena, padded to 16-mult segments ----
// Arena layout (bf16 elems):
//  [0..6)      plain msg li:  [160][96]   off = li*15360
//  [6..12)     plain upd li:  [80][160]   off = 92160 + li*12800
//  [12..14)    ar msg blk:    [320][160]  off = 168960 + blk*51200
//  [14..16)    ar upd blk:    [80][320]   off = 271360 + blk*25600
//  [16..18)    gru typ:       [256][128]  off = 322560 + typ*32768
__global__ void k_prepB(const float* __restrict__ Wm_plain, const float* __restrict__ Wu_plain,
                        const float* __restrict__ Wm_ar, const float* __restrict__ Wu_ar,
                        const float* __restrict__ Wi_map, const float* __restrict__ Wh_map,
                        const float* __restrict__ Wi_mem, const float* __restrict__ Wh_mem,
                        unsigned short* __restrict__ BtArena){
  int id = blockIdx.y;
  int Kp, elems, off;
  if (id < 6){ Kp=96;  elems=15360; off=id*15360; }
  else if (id < 12){ Kp=160; elems=12800; off=92160+(id-6)*12800; }
  else if (id < 14){ Kp=160; elems=51200; off=168960+(id-12)*51200; }
  else if (id < 16){ Kp=320; elems=25600; off=271360+(id-14)*25600; }
  else { Kp=128; elems=32768; off=322560+(id-16)*32768; }
  for (int g = blockIdx.x*256 + threadIdx.x; g < elems; g += 8*256){
    int c = g / Kp, k = g - c*Kp;
    float val = 0.f;
    if (id < 6){
      int li = id; int t = (c >= 80); int cc = c - t*80;
      if (cc < 70 && k < 70) val = Wm_plain[((li*2+t)*70 + k)*70 + cc];
    } else if (id < 12){
      int li = id-6;
      int kk = (k < 70) ? k : ((k >= 80 && k < 150) ? 70 + (k-80) : -1);
      if (c < 70 && kk >= 0) val = Wu_plain[(li*140 + kk)*70 + c];
    } else if (id < 14){
      int blk = id-12; int t = (c >= 160); int cc = c - t*160;
      int kk = (k < 70) ? k : ((k >= 80 && k < 150) ? 70 + (k-80) : -1);
      if (cc < 140 && kk >= 0) val = Wm_ar[(((blk*2+t)*140) + kk)*140 + cc];
    } else if (id < 16){
      int blk = id-14;
      int kk = (k < 70) ? k : ((k >= 80 && k < 150) ? 70 + (k-80)
               : ((k >= 160 && k < 300) ? 140 + (k-160) : -1));
      if (c < 70 && kk >= 0) val = Wu_ar[(blk*280 + kk)*70 + c];
    } else {
      int typ = id-16;
      const float* Wi = typ ? Wi_mem : Wi_map;
      const float* Wh = typ ? Wh_mem : Wh_map;
      if (c < 192) val = (k < 64) ? Wi[c*64 + k] : Wh[c*64 + (k-64)];
      else { int cc = c-192; val = (k >= 64) ? Wh[(128+cc)*64 + (k-64)] : 0.f; }
    }
    BtArena[off + g] = f2bf(val);
  }
}

// bias arena (fp32): [0..960) plain msg [160]x6; [960..1440) plain upd [80]x6;
// [1440..2080) ar msg [320]x2; [2080..2240) ar upd [80]x2; [2240..2752) gru [256]x2
__global__ void k_prepBias(const float* __restrict__ bm_plain, const float* __restrict__ bu_plain,
                           const float* __restrict__ bm_ar, const float* __restrict__ bu_ar,
                           const float* __restrict__ bi_map, const float* __restrict__ bh_map,
                           const float* __restrict__ bi_mem, const float* __restrict__ bh_mem,
                           float* __restrict__ biasA){
  for (int g = threadIdx.x; g < 2752; g += 256){
    float val = 0.f;
    if (g < 960){ int li=g/160, c=g%160; int t=(c>=80); int cc=c-t*80;
      if (cc<70) val = bm_plain[(li*2+t)*70 + cc]; }
    else if (g < 1440){ int u=g-960; int li=u/80, c=u%80; if (c<70) val = bu_plain[li*70+c]; }
    else if (g < 2080){ int u=g-1440; int blk=u/320, c=u%320; int t=(c>=160); int cc=c-t*160;
      if (cc<140) val = bm_ar[(blk*2+t)*140 + cc]; }
    else if (g < 2240){ int u=g-2080; int blk=u/80, c=u%80; if (c<70) val = bu_ar[blk*70+c]; }
    else { int u=g-2240; int typ=u/256, c=u%256;
      const float* bi = typ ? bi_mem : bi_map; const float* bh = typ ? bh_mem : bh_map;
      val = (c < 192) ? (bi[c]+bh[c]) : bh[128 + (c-192)]; }
    biasA[g] = val;
  }
}

// ---------------- init h = [one_hot(type,6) | zeros] bf16, stride 80 ----------------
__global__ void k_init_h(const int* __restrict__ type_idx, unsigned short* __restrict__ h, int N){
  int g = blockIdx.x*256 + threadIdx.x;
  if (g >= N*80) return;
  int n = g / 80, c = g - n*80;
  h[g] = (c < 6 && type_idx[n] == c) ? (unsigned short)0x3F80 : (unsigned short)0;
}

__global__ void k_compact(const int* __restrict__ type_idx, int* __restrict__ idxcat,
                          int* __restrict__ cnt, int N){
  int n = blockIdx.x*256 + threadIdx.x;
  if (n >= N) return;
  int t = type_idx[n];
  if (t == 0){ int p = atomicAdd(&cnt[0],1); if (p < CAPT) idxcat[p] = n; }
  else if (t == 5){ int p = atomicAdd(&cnt[1],1); if (p < CAPT) idxcat[CAPT+p] = n; }
}

// ---------------- embed gather: Xemb[r][s][k] bf16 ----------------
__global__ void k_xemb(const int* __restrict__ idxcat, const int* __restrict__ tokens,
                       const float* __restrict__ embed, unsigned short* __restrict__ Xemb){
  int g = blockIdx.x*256 + threadIdx.x;
  if (g >= R2*512) return;
  int r = g >> 9, rem = g & 511, s = rem >> 6, k = rem & 63;
  int nd = idxcat[r]; if (nd < 0) nd = 0;
  Xemb[g] = f2bf(embed[tokens[nd*8 + s]*64 + k]);
}

// ---------------- CSR build ----------------
__global__ void k_count(const int* __restrict__ edst, int* __restrict__ deg, int TE){
  int i = blockIdx.x*256 + threadIdx.x;
  if (i < TE) atomicAdd(&deg[edst[i]], 1);
}
__global__ void k_scan1(const int* __restrict__ deg, int* __restrict__ off,
                        int* __restrict__ bsum, int N){
  __shared__ int sh[256];
  int t = threadIdx.x; int base = blockIdx.x*2048;
  int v[8]; int s = 0;
  for (int i=0;i<8;i++){ int g = base + t*8 + i; int x = (g<N)? deg[g] : 0; v[i]=x; s+=x; }
  sh[t]=s; __syncthreads();
  for (int o=1;o<256;o<<=1){ int x = (t>=o)? sh[t-o]:0; __syncthreads(); sh[t]+=x; __syncthreads(); }
  if (t==255) bsum[blockIdx.x] = sh[255];
  int run = sh[t]-s;
  for (int i=0;i<8;i++){ int g = base + t*8 + i; if (g<N) off[g]=run; run+=v[i]; }
}
__global__ void k_scan2(int* bsum, int nb){
  if (threadIdx.x==0 && blockIdx.x==0){ int run=0; for(int b=0;b<nb;b++){ int x=bsum[b]; bsum[b]=run; run+=x; } }
}
__global__ void k_scan3(int* __restrict__ off, const int* __restrict__ bsum, int N, int total){
  int g = blockIdx.x*256+threadIdx.x;
  if (g < N) off[g] += bsum[g>>11];
  if (g == 0) off[N] = total;
}
__global__ void k_fill(const int* __restrict__ esrc, const int* __restrict__ edst,
                       const int* __restrict__ off, int* __restrict__ cur,
                       int* __restrict__ edata, int TE, int E){
  int i = blockIdx.x*256 + threadIdx.x;
  if (i >= TE) return;
  int d = edst[i];
  int pos = off[d] + atomicAdd(&cur[d], 1);
  edata[pos] = (esrc[i] << 1) | (i >= E ? 1 : 0);
}

// ======== wgemm: B-in-registers MFMA GEMM =========================================
// C = act([A0|A1|A2] @ B + bias). mode 1 = GRU (y = row region, B per region).
// act: 0 none, 1 gelu, 2 tanh, 3 = fused GRU cell update (requires CT==4, mode 1):
//   wave w's col tiles {w,w+4,w+8,w+12} == (r,z,n,hn) pre-activations for u=16w+m;
//   h' = (1-z)*tanh(n + (r-1)*hn) + z*h computed in-register, stored to C[row*64+u].
template<int RTR, int KT, int CT>
__global__ __launch_bounds__(256) void wgemm(
    const unsigned short* __restrict__ A0, int w0, int ldA0,
    const unsigned short* __restrict__ A1, int w1, int ldA1,
    const unsigned short* __restrict__ A2, int w2, int ldA2,
    const unsigned short* __restrict__ Bt, const unsigned short* __restrict__ Bt2, int KpB,
    const float* __restrict__ bias, const float* __restrict__ bias2,
    unsigned short* __restrict__ C, int ldC,
    int rows, int tiles, int act, int mode, const int* __restrict__ cnt)
{
  constexpr int Kpad = KT*32;
  constexpr int NRT  = RTR/16;
  constexpr int CPT  = (RTR*Kpad/8)/256;   // 16B chunks per thread per tile
  __shared__ __align__(16) unsigned short As[2][RTR*Kpad];
  int t = threadIdx.x;
  int lane = t & 63, m = lane & 15, q = lane >> 4, w = t >> 6;
  int rowBase = 0, tileBase = 0, rtEnd;
  const unsigned short* Bsel = Bt; const float* bsel = bias;
  if (mode == 1){
    rowBase = blockIdx.y * CAPT;
    int c = cnt[blockIdx.y]; if (c > CAPT) c = CAPT;
    rtEnd = (c + RTR - 1)/RTR;
    if (blockIdx.y == 1){ Bsel = Bt2; bsel = bias2; }
  } else {
    tileBase = blockIdx.y * (4*CT);
    rtEnd = (rows + RTR - 1)/RTR;
  }
  int tr = blockIdx.x;
  if (tr >= rtEnd) return;

  // ---- B fragments + bias into registers, once per block ----
  short8 breg[CT][KT]; float bv[CT]; bool val[CT]; int colr[CT];
  #pragma unroll
  for (int j=0;j<CT;j++){
    int tt = tileBase + w + 4*j;
    val[j] = (tt < tiles);
    int col = tt*16 + m;
    colr[j] = col;
    bv[j] = 0.f;
    if (val[j]){
      bv[j] = bsel[col];
      #pragma unroll
      for (int kt=0;kt<KT;kt++)
        breg[j][kt] = *(const short8*)&Bsel[(size_t)col*KpB + kt*32 + q*8];
    } else {
      #pragma unroll
      for (int kt=0;kt<KT;kt++) breg[j][kt] = (short8){0,0,0,0,0,0,0,0};
    }
  }

  int w01 = w0 + w1, w012 = w0 + w1 + w2;
  uint4 r[CPT];
  auto loadRegs = [&](int trr){
    #pragma unroll
    for (int i=0;i<CPT;i++){
      int c = i*256 + t;
      int row = c / (KT*4), kc = (c - row*(KT*4))*8;
      int gr = rowBase + trr*RTR + row;
      uint4 v = {0,0,0,0};
      if (gr < rows && kc < w012){
        const unsigned short* sp;
        if (kc < w0)       sp = A0 + (size_t)gr*ldA0 + kc;
        else if (kc < w01) sp = A1 + (size_t)gr*ldA1 + (kc - w0);
        else               sp = A2 + (size_t)gr*ldA2 + (kc - w01);
        v = *(const uint4*)sp;
      }
      r[i] = v;
    }
  };
  auto dsw = [&](int p){
    #pragma unroll
    for (int i=0;i<CPT;i++){
      int c = i*256 + t;
      int row = c / (KT*4), kc = (c - row*(KT*4))*8;
      *(uint4*)&As[p][row*Kpad + kc] = r[i];
    }
  };

  loadRegs(tr);
  dsw(0);
  int p = 0;
  for (;;){
    int nxt = tr + gridDim.x;
    bool hasNext = (nxt < rtEnd);
    if (hasNext) loadRegs(nxt);      // global loads in flight across the barrier
    __syncthreads();                 // buf[p] ready; prior reads of buf[p^1] done
    f32x4 acc[NRT][CT] = {};
    #pragma unroll
    for (int kt=0;kt<KT;kt++){
      short8 af[NRT];
      #pragma unroll
      for (int rt=0;rt<NRT;rt++)
        af[rt] = *(const short8*)&As[p][(rt*16+m)*Kpad + kt*32 + q*8];
      #pragma unroll
      for (int j=0;j<CT;j++)
        #pragma unroll
        for (int rt=0;rt<NRT;rt++)
          acc[rt][j] = __builtin_amdgcn_mfma_f32_16x16x32_bf16(af[rt], breg[j][kt], acc[rt][j], 0,0,0);
    }
    if constexpr (CT == 4){
      if (act == 3){
        // fused GRU cell update; Hprev == A1, u = colr[0], ldC == 64
        int u = colr[0];
        #pragma unroll
        for (int rt=0;rt<NRT;rt++){
          int rbase = rowBase + tr*RTR + rt*16 + q*4;
          #pragma unroll
          for (int i=0;i<4;i++){
            int grow = rbase + i;
            float rr = fsig_(acc[rt][0][i] + bv[0]);
            float zz = fsig_(acc[rt][1][i] + bv[1]);
            float hn = acc[rt][3][i] + bv[3];
            float nn = ftanh_(acc[rt][2][i] + bv[2] + (rr - 1.f)*hn);
            float hp = bf2f(A1[(size_t)grow*64 + u]);
            C[(size_t)grow*64 + u] = f2bf((1.f - zz)*nn + zz*hp);
          }
        }
        if (!hasNext) break;
        dsw(p^1);
        p ^= 1; tr = nxt;
        continue;
      }
    }
    bool tfull = (tr*RTR + RTR <= rows);
#define EPILOG(CHK)                                                         \
    _Pragma("unroll")                                                       \
    for (int rt=0;rt<NRT;rt++){                                             \
      int rbase = rowBase + tr*RTR + rt*16 + q*4;                           \
      _Pragma("unroll")                                                     \
      for (int j=0;j<CT;j++){                                               \
        if (!val[j]) continue;                                              \
        _Pragma("unroll")                                                   \
        for (int i=0;i<4;i++){                                              \
          int grow = rbase + i;                                             \
          if (CHK && grow >= rows) continue;                                \
          float v = acc[rt][j][i] + bv[j];                                  \
          if (act == 1) v = fgelu_(v);                                      \
          else if (act == 2) v = ftanh_(v);                                 \
          C[(size_t)grow*ldC + colr[j]] = f2bf(v);                          \
        }                                                                   \
      }                                                                     \
    }
    if (tfull){ EPILOG(false) } else { EPILOG(true) }
#undef EPILOG
    if (!hasNext) break;
    dsw(p^1);                        // safe: all reads of buf[p^1] were pre-barrier
    p ^= 1; tr = nxt;
  }
}

__global__ void k_scatter_h(const int* __restrict__ idxcat, const unsigned short* __restrict__ Hlast,
                            unsigned short* __restrict__ h){
  int g = blockIdx.x*256 + threadIdx.x;     // R2*64
  int row = g >> 6, u = g & 63;
  int nd = idxcat[row];
  if (nd >= 0) h[(size_t)nd*80 + 6 + u] = Hlast[g];
}

// ---------------- CSR gather + segment max, bf16, uint(2-col) loads, 4-edge unroll ----
__global__ __launch_bounds__(256) void k_aggregate(
    const int* __restrict__ off, const int* __restrict__ edata,
    const unsigned short* __restrict__ P2, int ldP, int off1,
    unsigned short* __restrict__ agg, int M, int N)
{
  int node = blockIdx.x*4 + (threadIdx.x >> 6);
  int lane = threadIdx.x & 63;
  if (node >= N) return;
  int e0 = off[node], e1 = off[node+1];
  const float NEG = -__builtin_inff();
  int c0 = 2*lane, c1 = 128 + 2*lane;
  bool a0 = c0 < M, a1 = c1 < M;
  float v00 = NEG, v01 = NEG, v10 = NEG, v11 = NEG;
  int e = e0;
  for (; e + 4 <= e1; e += 4){
    int w0 = edata[e], w1 = edata[e+1], w2 = edata[e+2], w3 = edata[e+3];
    const unsigned short* r0 = P2 + (size_t)(w0>>1)*ldP + (w0&1)*off1;
    const unsigned short* r1 = P2 + (size_t)(w1>>1)*ldP + (w1&1)*off1;
    const unsigned short* r2 = P2 + (size_t)(w2>>1)*ldP + (w2&1)*off1;
    const unsigned short* r3 = P2 + (size_t)(w3>>1)*ldP + (w3&1)*off1;
    if (a0){
      unsigned int u0 = *(const unsigned int*)(r0 + c0);
      unsigned int u1 = *(const unsigned int*)(r1 + c0);
      unsigned int u2 = *(const unsigned int*)(r2 + c0);
      unsigned int u3 = *(const unsigned int*)(r3 + c0);
      v00 = fmaxf(v00, fmaxf(fmaxf(bf2f((unsigned short)u0), bf2f((unsigned short)u1)),
                             fmaxf(bf2f((unsigned short)u2), bf2f((unsigned short)u3))));
      v01 = fmaxf(v01, fmaxf(fmaxf(bf2f((unsigned short)(u0>>16)), bf2f((unsigned short)(u1>>16))),
                             fmaxf(bf2f((unsigned short)(u2>>16)), bf2f((unsigned short)(u3>>16)))));
    }
    if (a1){
      unsigned int u0 = *(const unsigned int*)(r0 + c1);
      unsigned int u1 = *(const unsigned int*)(r1 + c1);
      unsigned int u2 = *(const unsigned int*)(r2 + c1);
      unsigned int u3 = *(const unsigned int*)(r3 + c1);
      v10 = fmaxf(v10, fmaxf(fmaxf(bf2f((unsigned short)u0), bf2f((unsigned short)u1)),
                             fmaxf(bf2f((unsigned short)u2), bf2f((unsigned short)u3))));
      v11 = fmaxf(v11, fmaxf(fmaxf(bf2f((unsigned short)(u0>>16)), bf2f((unsigned short)(u1>>16))),
                             fmaxf(bf2f((unsigned short)(u2>>16)), bf2f((unsigned short)(u3>>16)))));
    }
  }
  for (; e < e1; e++){
    int w = edata[e];
    const unsigned short* r0 = P2 + (size_t)(w>>1)*ldP + (w&1)*off1;
    if (a0){
      unsigned int u0 = *(const unsigned int*)(r0 + c0);
      v00 = fmaxf(v00, bf2f((unsigned short)u0));
      v01 = fmaxf(v01, bf2f((unsigned short)(u0>>16)));
    }
    if (a1){
      unsigned int u0 = *(const unsigned int*)(r0 + c1);
      v10 = fmaxf(v10, bf2f((unsigned short)u0));
      v11 = fmaxf(v11, bf2f((unsigned short)(u0>>16)));
    }
  }
  if (a0){
    unsigned int o = (unsigned int)f2bf(v00 == NEG ? 0.f : v00)
                   | ((unsigned int)f2bf(v01 == NEG ? 0.f : v01) << 16);
    *(unsigned int*)(agg + (size_t)node*M + c0) = o;
  }
  if (a1){
    unsigned int o = (unsigned int)f2bf(v10 == NEG ? 0.f : v10)
                   | ((unsigned int)f2bf(v11 == NEG ? 0.f : v11) << 16);
    *(unsigned int*)(agg + (size_t)node*M + c1) = o;
  }
}

// ---------------- final head ----------------
__global__ void k_head(const unsigned short* __restrict__ h, const int* __restrict__ entry,
                       const float* __restrict__ W1, const float* __restrict__ b1,
                       const float* __restrict__ W2, const float* __restrict__ b2,
                       float* __restrict__ out){
  __shared__ float x[70], x1[70];
  int t = threadIdx.x;
  if (t < 70) x[t] = bf2f(h[(size_t)(*entry)*80 + t]);
  __syncthreads();
  if (t < 70){
    float s = b1[t];
    for (int i=0;i<70;i++) s += x[i]*W1[i*70 + t];
    x1[t] = fmaxf(s, 0.f);
  }
  __syncthreads();
  if (t < 640){
    float s = b2[t];
    for (int i=0;i<70;i++) s += x1[i]*W2[i*640 + t];
    out[t] = s;
  }
}

extern "C" void kernel_launch(void* const* d_in, const int* in_sizes, int n_in,
                              void* d_out, int out_size, void* d_ws, size_t ws_size,
                              hipStream_t stream) {
  const int*   tokens   = (const int*)d_in[0];
  const int*   type_idx = (const int*)d_in[1];
  const int*   esrc     = (const int*)d_in[2];
  const int*   edst     = (const int*)d_in[3];
  const int*   entry    = (const int*)d_in[4];
  const float* embed    = (const float*)d_in[5];
  const float* Wi_map   = (const float*)d_in[6];
  const float* Wh_map   = (const float*)d_in[7];
  const float* bi_map   = (const float*)d_in[8];
  const float* bh_map   = (const float*)d_in[9];
  const float* Wi_mem   = (const float*)d_in[10];
  const float* Wh_mem   = (const float*)d_in[11];
  const float* bi_mem   = (const float*)d_in[12];
  const float* bh_mem   = (const float*)d_in[13];
  const float* Wm_plain = (const float*)d_in[14];
  const float* bm_plain = (const float*)d_in[15];
  const float* Wu_plain = (const float*)d_in[16];
  const float* bu_plain = (const float*)d_in[17];
  const float* Wm_ar    = (const float*)d_in[18];
  const float* bm_ar    = (const float*)d_in[19];
  const float* Wu_ar    = (const float*)d_in[20];
  const float* bu_ar    = (const float*)d_in[21];
  const float* W1 = (const float*)d_in[22];
  const float* b1 = (const float*)d_in[23];
  const float* W2 = (const float*)d_in[24];
  const float* b2 = (const float*)d_in[25];
  float* out = (float*)d_out;

  const int N  = in_sizes[1];      // 100000
  const int TE = in_sizes[2];      // 500000
  const int E  = TE / 2;

  char* p = (char*)d_ws;
  auto alloc = [&](size_t bytes)->char* { char* r = p; p += (bytes + 255) & ~(size_t)255; return r; };
  unsigned short* hA  = (unsigned short*)alloc((size_t)N*80*2);
  unsigned short* hB  = (unsigned short*)alloc((size_t)N*80*2);
  unsigned short* hC  = (unsigned short*)alloc((size_t)N*80*2);
  unsigned short* P2  = (unsigned short*)alloc((size_t)N*320*2);   // also Xemb overlay
  unsigned short* agg = (unsigned short*)alloc((size_t)N*160*2);
  unsigned short* Hb0 = (unsigned short*)alloc((size_t)R2*64*2);
  unsigned short* Hb1 = (unsigned short*)alloc((size_t)R2*64*2);
  int* deg    = (int*)alloc((size_t)N*4);
  int* curp   = (int*)alloc((size_t)N*4);
  int* off    = (int*)alloc((size_t)(N+8)*4);
  int* edata  = (int*)alloc((size_t)TE*4);
  int* sbsum  = (int*)alloc(256*4);
  int* cnt    = (int*)alloc(16*4);
  int* idxcat = (int*)alloc((size_t)R2*4);
  unsigned short* BtA = (unsigned short*)alloc(388096*2);
  float* biasA = (float*)alloc(2752*4);
  unsigned short* Xemb = P2;                   // [R2][512] bf16, dead before P2 is used

  hipMemsetAsync(idxcat, 0xFF, (size_t)R2*4, stream);
  hipMemsetAsync(cnt,    0,    16*4, stream);
  hipMemsetAsync(deg,    0,    (size_t)N*4, stream);
  hipMemsetAsync(curp,   0,    (size_t)N*4, stream);
  hipMemsetAsync(Hb0,    0,    (size_t)R2*64*2, stream);

  k_prepB<<<dim3(8,18), 256, 0, stream>>>(Wm_plain, Wu_plain, Wm_ar, Wu_ar,
                                          Wi_map, Wh_map, Wi_mem, Wh_mem, BtA);
  k_prepBias<<<1, 256, 0, stream>>>(bm_plain, bu_plain, bm_ar, bu_ar,
                                    bi_map, bh_map, bi_mem, bh_mem, biasA);
  k_init_h<<<(N*80+255)/256, 256, 0, stream>>>(type_idx, hA, N);
  k_compact<<<(N+255)/256, 256, 0, stream>>>(type_idx, idxcat, cnt, N);

  k_count<<<(TE+255)/256, 256, 0, stream>>>(edst, deg, TE);
  int nb = (N + 2047)/2048;
  k_scan1<<<nb, 256, 0, stream>>>(deg, off, sbsum, N);
  k_scan2<<<1, 64, 0, stream>>>(sbsum, nb);
  k_scan3<<<(N+255)/256, 256, 0, stream>>>(off, sbsum, N, TE);
  k_fill<<<(TE+255)/256, 256, 0, stream>>>(esrc, edst, off, curp, edata, TE, E);

  k_xemb<<<(R2*512)/256, 256, 0, stream>>>(idxcat, tokens, embed, Xemb);

  // ---- GRU: 8 steps, pointwise fused into gemm epilogue (act=3) ----
  const unsigned short* BtG0 = BtA + 322560;
  const unsigned short* BtG1 = BtA + 322560 + 32768;
  const float* bG0 = biasA + 2240;
  const float* bG1 = biasA + 2240 + 256;
  unsigned short* Hcur = Hb0; unsigned short* Hnxt = Hb1;
  for (int s = 0; s < 8; s++){
    wgemm<64,4,4><<<dim3(CAPT/64, 2), 256, 0, stream>>>(
        Xemb + s*64, 64, 512,  Hcur, 64, 64,  nullptr, 0, 0,
        BtG0, BtG1, 128, bG0, bG1,
        Hnxt, 64, R2, 16, 3 /*gru fuse*/, 1, cnt);
    unsigned short* tmp = Hcur; Hcur = Hnxt; Hnxt = tmp;
  }
  k_scatter_h<<<(R2*64)/256, 256, 0, stream>>>(idxcat, Hcur, hA);

  // ---- 2 blocks x (3 plain MP + concat-residual AR MP) ----
  unsigned short* cur = hA; unsigned short* f1 = hB; unsigned short* f2 = hC;
  int li = 0;
  for (int blk = 0; blk < 2; blk++){
    unsigned short* saved = cur;
    unsigned short* ins[3]  = {cur, f1, f2};
    unsigned short* outs[3] = {f1, f2, f1};
    for (int j = 0; j < 3; j++){
      unsigned short* X = ins[j]; unsigned short* Yo = outs[j];
      // msg: [N,80] @ [96->160] (both edge types fused in cols)
      wgemm<64,3,3><<<dim3(1024,1), 256, 0, stream>>>(
          X, 80, 80,  nullptr, 0, 0,  nullptr, 0, 0,
          BtA + li*15360, nullptr, 96, biasA + li*160, nullptr,
          P2, 160, N, 10, 0, 0, nullptr);
      k_aggregate<<<(N+3)/4, 256, 0, stream>>>(off, edata, P2, 160, 80, agg, 80, N);
      // upd: [N,80|80] @ [160->80]
      wgemm<64,5,2><<<dim3(1024,1), 256, 0, stream>>>(
          X, 80, 80,  agg, 80, 80,  nullptr, 0, 0,
          BtA + 92160 + li*12800, nullptr, 160, biasA + 960 + li*80, nullptr,
          Yo, 80, N, 5, 0, 0, nullptr);
      li++;
    }
    // AR msg: [N,80|80] @ [160->320], gelu; y splits 20 col tiles into 12+8
    wgemm<64,5,3><<<dim3(512,2), 256, 0, stream>>>(
        saved, 80, 80,  f1, 80, 80,  nullptr, 0, 0,
        BtA + 168960 + blk*51200, nullptr, 160, biasA + 1440 + blk*320, nullptr,
        P2, 320, N, 20, 1 /*gelu*/, 0, nullptr);
    k_aggregate<<<(N+3)/4, 256, 0, stream>>>(off, edata, P2, 320, 160, agg, 160, N);
    // AR upd: [N,80|80|160] @ [320->80], tanh; 32-row tiles (K=320 LDS)
    wgemm<32,10,2><<<dim3(1024,1), 256, 0, stream>>>(
        saved, 80, 80,  f1, 80, 80,  agg, 160, 160,
        BtA + 271360 + blk*25600, nullptr, 320, biasA + 2080 + blk*80, nullptr,
        f2, 80, N, 5, 2 /*tanh*/, 0, nullptr);
    unsigned short* t3 = cur; cur = f2; f2 = t3;
  }

  k_head<<<1, 640, 0, stream>>>(cur, entry, W1, b1, W2, b2, out);
}